// Round 1
// baseline (683.298 us; speedup 1.0000x reference)
//
#include <hip/hip_runtime.h>

#define NEGF -9e15f

// ---------- bf16 helpers (OCP bf16 via bit ops, RTN-even) ----------
__device__ __forceinline__ unsigned short f2bf(float x) {
  union { float f; unsigned int u; } c; c.f = x;
  unsigned int r = c.u + 0x7fffu + ((c.u >> 16) & 1u);
  return (unsigned short)(r >> 16);
}
__device__ __forceinline__ float bf2f(unsigned short v) {
  union { float f; unsigned int u; } c; c.u = ((unsigned int)v) << 16;
  return c.f;
}

// ---------------------------------------------------------------
// C[M][N] = A[M][K] @ op(B) + bias
// TRANSB=true : B is [N][K] (torch Linear weight), computes A @ B^T
// TRANSB=false: B is [K][N], computes A @ B
// BM=BN=64, BK=16, 256 threads, 4x4 micro-tile.
// ---------------------------------------------------------------
template<bool TRANSB>
__global__ __launch_bounds__(256) void gemm64(
    const float* __restrict__ A, const float* __restrict__ B,
    const float* __restrict__ bias, float* __restrict__ C,
    int M, int N, int K)
{
  __shared__ float As[16][68];   // [k][m], pad 4 for bank spread + f4 align
  __shared__ float Bs[16][68];   // [k][n]
  const int t  = threadIdx.x;
  const int tx = t & 15, ty = t >> 4;
  const int bm = blockIdx.y * 64;
  const int bn = blockIdx.x * 64;

  float acc[4][4] = {};

  for (int k0 = 0; k0 < K; k0 += 16) {
    // stage A tile transposed: 64 rows x 16 k
    {
      const int row = t >> 2, kk = (t & 3) * 4;
      const float4 v = *(const float4*)(A + (size_t)(bm + row) * K + k0 + kk);
      As[kk + 0][row] = v.x; As[kk + 1][row] = v.y;
      As[kk + 2][row] = v.z; As[kk + 3][row] = v.w;
    }
    if (TRANSB) {
      const int col = t >> 2, kk = (t & 3) * 4;
      const float4 v = *(const float4*)(B + (size_t)(bn + col) * K + k0 + kk);
      Bs[kk + 0][col] = v.x; Bs[kk + 1][col] = v.y;
      Bs[kk + 2][col] = v.z; Bs[kk + 3][col] = v.w;
    } else {
      const int kr = t >> 4, n4 = (t & 15) * 4;
      *(float4*)&Bs[kr][n4] = *(const float4*)(B + (size_t)(k0 + kr) * N + bn + n4);
    }
    __syncthreads();
    #pragma unroll
    for (int kk = 0; kk < 16; ++kk) {
      const float4 a = *(const float4*)&As[kk][ty * 4];
      const float4 w = *(const float4*)&Bs[kk][tx * 4];
      const float av[4] = {a.x, a.y, a.z, a.w};
      const float wv[4] = {w.x, w.y, w.z, w.w};
      #pragma unroll
      for (int i = 0; i < 4; ++i)
        #pragma unroll
        for (int j = 0; j < 4; ++j)
          acc[i][j] = fmaf(av[i], wv[j], acc[i][j]);
    }
    __syncthreads();
  }

  float4 bv4 = make_float4(0.f, 0.f, 0.f, 0.f);
  if (bias) bv4 = *(const float4*)(bias + bn + tx * 4);
  #pragma unroll
  for (int i = 0; i < 4; ++i) {
    float4 r;
    r.x = acc[i][0] + bv4.x; r.y = acc[i][1] + bv4.y;
    r.z = acc[i][2] + bv4.z; r.w = acc[i][3] + bv4.w;
    *(float4*)(C + (size_t)(bm + ty * 4 + i) * N + bn + tx * 4) = r;
  }
}

// bov[g] = sum_f Wo[g][f] * bv[f]   (1024 outputs, one wave per g)
__global__ __launch_bounds__(256) void bov_kernel(
    const float* __restrict__ Wo, const float* __restrict__ bv,
    float* __restrict__ bov)
{
  const int g    = blockIdx.x * 4 + (threadIdx.x >> 6);
  const int lane = threadIdx.x & 63;
  float acc = 0.f;
  for (int f = lane; f < 1024; f += 64)
    acc = fmaf(Wo[(size_t)g * 1024 + f], bv[f], acc);
  #pragma unroll
  for (int off = 32; off > 0; off >>= 1) acc += __shfl_down(acc, off);
  if (lane == 0) bov[g] = acc;
}

// ---------------------------------------------------------------
// Fused attention: one block per (qtile=64, h, b), 256 threads.
// logits -> mask+bias -> softmax -> att_mean atomics -> P (bf16, LDS)
// -> PV against VW -> out (+bo).
// thread (tx,ty): q rows = ty*4..+3, k cols = {j4*64 + tx*4 + jj}
// ---------------------------------------------------------------
__global__ __launch_bounds__(256) void attn_kernel(
    const float* __restrict__ Q,  const float* __restrict__ Kp,
    const float* __restrict__ VW, const int* __restrict__ adj,
    const float* __restrict__ lab, const float* __restrict__ bo,
    float* __restrict__ outp, float* __restrict__ attm)
{
  const int t  = threadIdx.x;
  const int tx = t & 15, ty = t >> 4;
  const int qt = blockIdx.x, h = blockIdx.y, b = blockIdx.z;
  const int q0 = qt * 64;

  // LDS overlay: phase1 {Qs[64][68], Kc[64][68]} ; phase2 {Ps[256][72] bf16, VWc[64][68]}
  __shared__ __align__(16) char smem[54272];
  float (*Qs)[68]           = (float (*)[68])smem;                  // [d][q]
  float (*Kc)[68]           = (float (*)[68])(smem + 17408);        // [d][k_local]
  unsigned short (*Ps)[72]  = (unsigned short (*)[72])smem;         // [k][q] bf16
  float (*VWc)[68]          = (float (*)[68])(smem + 36864);        // [k_local][d]

  // ---- stage Q^T ----
  {
    const int qr = t >> 2, d0 = (t & 3) * 4;
    const float* qrow = Q + (size_t)(b * 256 + q0 + qr) * 1024 + h * 64;
    #pragma unroll
    for (int j = 0; j < 4; ++j) {
      const float4 v = *(const float4*)(qrow + d0 + j * 16);
      Qs[d0 + j * 16 + 0][qr] = v.x;
      Qs[d0 + j * 16 + 1][qr] = v.y;
      Qs[d0 + j * 16 + 2][qr] = v.z;
      Qs[d0 + j * 16 + 3][qr] = v.w;
    }
  }

  // ---- logits: QK^T over 4 k-chunks of 64 ----
  float l[4][16];
  #pragma unroll
  for (int kc = 0; kc < 4; ++kc) {
    __syncthreads();
    {
      const int kl = t >> 2, d0 = (t & 3) * 4;
      const float* krow = Kp + (size_t)(b * 256 + kc * 64 + kl) * 1024 + h * 64;
      #pragma unroll
      for (int j = 0; j < 4; ++j) {
        const float4 v = *(const float4*)(krow + d0 + j * 16);
        Kc[d0 + j * 16 + 0][kl] = v.x;
        Kc[d0 + j * 16 + 1][kl] = v.y;
        Kc[d0 + j * 16 + 2][kl] = v.z;
        Kc[d0 + j * 16 + 3][kl] = v.w;
      }
    }
    __syncthreads();
    float acc[4][4] = {};
    #pragma unroll 8
    for (int d = 0; d < 64; ++d) {
      const float4 a = *(const float4*)&Qs[d][ty * 4];
      const float4 w = *(const float4*)&Kc[d][tx * 4];
      const float av[4] = {a.x, a.y, a.z, a.w};
      const float wv[4] = {w.x, w.y, w.z, w.w};
      #pragma unroll
      for (int i = 0; i < 4; ++i)
        #pragma unroll
        for (int jj = 0; jj < 4; ++jj)
          acc[i][jj] = fmaf(av[i], wv[jj], acc[i][jj]);
    }
    #pragma unroll
    for (int i = 0; i < 4; ++i)
      #pragma unroll
      for (int jj = 0; jj < 4; ++jj)
        l[i][kc * 4 + jj] = acc[i][jj];
  }

  // ---- mask + bias + softmax over k (16 lanes x 16 vals per row) ----
  const float scale = 0.125f;  // 1/sqrt(64)
  float inv[4];
  #pragma unroll
  for (int i = 0; i < 4; ++i) {
    const size_t qg = (size_t)b * 256 + q0 + ty * 4 + i;
    const int*   arow = adj + qg * 256;
    const float* brow = lab + qg * 256;
    #pragma unroll
    for (int j4 = 0; j4 < 4; ++j4) {
      const int kb = j4 * 64 + tx * 4;
      const int4   a4 = *(const int4*)(arow + kb);
      const float4 b4 = *(const float4*)(brow + kb);
      float* lp = &l[i][j4 * 4];
      lp[0] = (a4.x > 0 ? lp[0] * scale : NEGF) + b4.x;
      lp[1] = (a4.y > 0 ? lp[1] * scale : NEGF) + b4.y;
      lp[2] = (a4.z > 0 ? lp[2] * scale : NEGF) + b4.z;
      lp[3] = (a4.w > 0 ? lp[3] * scale : NEGF) + b4.w;
    }
    float m = l[i][0];
    #pragma unroll
    for (int n = 1; n < 16; ++n) m = fmaxf(m, l[i][n]);
    #pragma unroll
    for (int off = 1; off < 16; off <<= 1) m = fmaxf(m, __shfl_xor(m, off));
    float s = 0.f;
    #pragma unroll
    for (int n = 0; n < 16; ++n) { l[i][n] = __expf(l[i][n] - m); s += l[i][n]; }
    #pragma unroll
    for (int off = 1; off < 16; off <<= 1) s += __shfl_xor(s, off);
    inv[i] = 1.f / s;
  }

  __syncthreads();  // Qs/Kc dead; Ps overlays them

  // ---- att_mean (sum over heads / 16) via atomics ----
  #pragma unroll
  for (int i = 0; i < 4; ++i) {
    const size_t qg = (size_t)b * 256 + q0 + ty * 4 + i;
    float* amrow = attm + qg * 256;
    const float w = inv[i] * 0.0625f;
    #pragma unroll
    for (int n = 0; n < 16; ++n) {
      const int kg = (n >> 2) * 64 + tx * 4 + (n & 3);
      atomicAdd(amrow + kg, l[i][n] * w);
    }
  }

  // ---- P -> LDS (bf16, [k][q] so PV reads are contiguous in q) ----
  #pragma unroll
  for (int n = 0; n < 16; ++n) {
    const int kg = (n >> 2) * 64 + tx * 4 + (n & 3);
    ushort4 u;
    u.x = f2bf(l[0][n] * inv[0]);
    u.y = f2bf(l[1][n] * inv[1]);
    u.z = f2bf(l[2][n] * inv[2]);
    u.w = f2bf(l[3][n] * inv[3]);
    *(ushort4*)&Ps[kg][ty * 4] = u;
  }

  // ---- PV: out[q][d] = sum_k P[k][q] * VW[k][d] ----
  float o[4][4] = {};
  #pragma unroll
  for (int kc = 0; kc < 4; ++kc) {
    __syncthreads();
    {
      const int kl = t >> 2, d0 = (t & 3) * 4;
      const float* vrow = VW + (size_t)(b * 256 + kc * 64 + kl) * 1024 + h * 64;
      #pragma unroll
      for (int j = 0; j < 4; ++j)
        *(float4*)&VWc[kl][d0 + j * 16] = *(const float4*)(vrow + d0 + j * 16);
    }
    __syncthreads();
    #pragma unroll 4
    for (int kl = 0; kl < 64; ++kl) {
      const ushort4 pu = *(const ushort4*)&Ps[kc * 64 + kl][ty * 4];
      const float4  w  = *(const float4*)&VWc[kl][tx * 4];
      const float pv[4] = {bf2f(pu.x), bf2f(pu.y), bf2f(pu.z), bf2f(pu.w)};
      const float wv[4] = {w.x, w.y, w.z, w.w};
      #pragma unroll
      for (int i = 0; i < 4; ++i)
        #pragma unroll
        for (int j = 0; j < 4; ++j)
          o[i][j] = fmaf(pv[i], wv[j], o[i][j]);
    }
  }

  // ---- epilogue: + bo, store ----
  const float4 bo4 = *(const float4*)(bo + h * 64 + tx * 4);
  #pragma unroll
  for (int i = 0; i < 4; ++i) {
    float4 r;
    r.x = o[i][0] + bo4.x; r.y = o[i][1] + bo4.y;
    r.z = o[i][2] + bo4.z; r.w = o[i][3] + bo4.w;
    *(float4*)(outp + (size_t)(b * 256 + q0 + ty * 4 + i) * 1024 + h * 64 + tx * 4) = r;
  }
}

// ---------------------------------------------------------------
extern "C" void kernel_launch(void* const* d_in, const int* in_sizes, int n_in,
                              void* d_out, int out_size, void* d_ws, size_t ws_size,
                              hipStream_t stream)
{
  const float* obj   = (const float*)d_in[0];
  const float* cross = (const float*)d_in[1];
  const int*   adj   = (const int*)d_in[2];
  const float* lab   = (const float*)d_in[3];
  const float* Wq    = (const float*)d_in[4];
  const float* bq    = (const float*)d_in[5];
  const float* Wk    = (const float*)d_in[6];
  const float* bk    = (const float*)d_in[7];
  const float* Wv    = (const float*)d_in[8];
  const float* bv    = (const float*)d_in[9];
  const float* Wo    = (const float*)d_in[10];
  const float* bo    = (const float*)d_in[11];

  float* out  = (float*)d_out;
  float* attm = out + (size_t)16 * 256 * 1024;      // out is [B,N,F] then att_mean [B,N,N]

  // workspace: Q(4M) K(4M) VW(4M) Wov(1M) bov(1K) floats  (~52 MB)
  float* wsf  = (float*)d_ws;
  float* Qb   = wsf;
  float* Kb   = wsf + (size_t)4 * 1024 * 1024;
  float* VWb  = wsf + (size_t)8 * 1024 * 1024;
  float* Wov  = wsf + (size_t)12 * 1024 * 1024;
  float* bov  = wsf + (size_t)13 * 1024 * 1024;

  // fold V-projection + grouped output conv:  VW = cross @ (Wo@Wv)^T + Wo@bv
  bov_kernel<<<256, 256, 0, stream>>>(Wo, bv, bov);
  gemm64<false><<<dim3(16, 16), 256, 0, stream>>>(Wo, Wv, nullptr, Wov, 1024, 1024, 1024);

  gemm64<true><<<dim3(16, 64), 256, 0, stream>>>(obj,   Wq,  bq,  Qb,  4096, 1024, 1024);
  gemm64<true><<<dim3(16, 64), 256, 0, stream>>>(cross, Wk,  bk,  Kb,  4096, 1024, 1024);
  gemm64<true><<<dim3(16, 64), 256, 0, stream>>>(cross, Wov, bov, VWb, 4096, 1024, 1024);

  hipMemsetAsync(attm, 0, (size_t)16 * 256 * 256 * sizeof(float), stream);
  attn_kernel<<<dim3(4, 16, 16), 256, 0, stream>>>(Qb, Kb, VWb, adj, lab, bo, out, attm);
}

// Round 2
// 198.813 us; speedup vs baseline: 3.4369x; 3.4369x over previous
//
#include <hip/hip_runtime.h>

#define NEGF -9e15f

typedef __attribute__((ext_vector_type(8))) unsigned short u16x8;
typedef __attribute__((ext_vector_type(8))) short          s16x8;
typedef __attribute__((ext_vector_type(4))) float          f32x4;

// ---------- bf16 helpers (RTN-even) ----------
__device__ __forceinline__ unsigned short f2bf(float x) {
  union { float f; unsigned int u; } c; c.f = x;
  unsigned int r = c.u + 0x7fffu + ((c.u >> 16) & 1u);
  return (unsigned short)(r >> 16);
}
__device__ __forceinline__ float bf2f(unsigned short v) {
  union { float f; unsigned int u; } c; c.u = ((unsigned int)v) << 16;
  return c.f;
}

// ---------- fp32 -> bf16 elementwise ----------
__global__ __launch_bounds__(256) void cvt_bf16(
    const float* __restrict__ in, unsigned short* __restrict__ out, int n)
{
  const int i = (blockIdx.x * 256 + threadIdx.x) * 4;
  if (i < n) {
    const float4 v = *(const float4*)(in + i);
    ushort4 o; o.x = f2bf(v.x); o.y = f2bf(v.y); o.z = f2bf(v.z); o.w = f2bf(v.w);
    *(ushort4*)(out + i) = o;
  }
}

// ---------- fp32 -> bf16 transposed (out[c][r] = in[r][c]) ----------
__global__ __launch_bounds__(256) void tcvt_bf16(
    const float* __restrict__ in, unsigned short* __restrict__ out, int R, int C)
{
  __shared__ float tile[32][33];
  const int bc = blockIdx.x * 32, br = blockIdx.y * 32;
  const int tx = threadIdx.x & 31, ty8 = threadIdx.x >> 5;
  #pragma unroll
  for (int j = 0; j < 32; j += 8)
    tile[ty8 + j][tx] = in[(size_t)(br + ty8 + j) * C + bc + tx];
  __syncthreads();
  #pragma unroll
  for (int j = 0; j < 32; j += 8)
    out[(size_t)(bc + ty8 + j) * R + br + tx] = f2bf(tile[tx][ty8 + j]);
}

// bov[g] = sum_f Wo[g][f] * bv[f]
__global__ __launch_bounds__(256) void bov_kernel(
    const float* __restrict__ Wo, const float* __restrict__ bv,
    float* __restrict__ bov)
{
  const int g    = blockIdx.x * 4 + (threadIdx.x >> 6);
  const int lane = threadIdx.x & 63;
  float acc = 0.f;
  for (int f = lane; f < 1024; f += 64)
    acc = fmaf(Wo[(size_t)g * 1024 + f], bv[f], acc);
  #pragma unroll
  for (int off = 32; off > 0; off >>= 1) acc += __shfl_down(acc, off);
  if (lane == 0) bov[g] = acc;
}

// ---------------------------------------------------------------
// MFMA GEMM: C[M][N] = A[M][K] @ B[N][K]^T + bias   (bf16 in, fp32 acc)
// BM=128 BN=64 BK=64, 256 threads = 4 waves (wave tile 64x32).
// OUT_BF16: 1 -> bf16 C, 0 -> fp32 C.
// ---------------------------------------------------------------
template<int OUT_BF16>
__global__ __launch_bounds__(256) void gemm_mfma_bt(
    const unsigned short* __restrict__ A,
    const unsigned short* __restrict__ Bw,
    const float* __restrict__ bias,
    void* __restrict__ Cout,
    int M, int N, int K)
{
  __shared__ unsigned short Asm[128][72];
  __shared__ unsigned short Bsm[64][72];
  const int t = threadIdx.x;
  const int lane = t & 63, w = t >> 6;
  const int wm = w >> 1, wn = w & 1;
  const int bm = blockIdx.y * 128, bn = blockIdx.x * 64;

  f32x4 acc[4][2] = {};

  const int sr  = t >> 3;          // 0..31
  const int skq = (t & 7) * 8;     // 0..56
  const int fr  = lane & 15;
  const int kf  = (lane >> 4) * 8;

  for (int k0 = 0; k0 < K; k0 += 64) {
    const u16x8 a0 = *(const u16x8*)(A  + (size_t)(bm + sr)      * K + k0 + skq);
    const u16x8 a1 = *(const u16x8*)(A  + (size_t)(bm + sr + 32) * K + k0 + skq);
    const u16x8 a2 = *(const u16x8*)(A  + (size_t)(bm + sr + 64) * K + k0 + skq);
    const u16x8 a3 = *(const u16x8*)(A  + (size_t)(bm + sr + 96) * K + k0 + skq);
    const u16x8 b0 = *(const u16x8*)(Bw + (size_t)(bn + sr)      * K + k0 + skq);
    const u16x8 b1 = *(const u16x8*)(Bw + (size_t)(bn + sr + 32) * K + k0 + skq);
    __syncthreads();   // previous iter's frag reads done before overwrite
    *(u16x8*)&Asm[sr][skq]      = a0;
    *(u16x8*)&Asm[sr + 32][skq] = a1;
    *(u16x8*)&Asm[sr + 64][skq] = a2;
    *(u16x8*)&Asm[sr + 96][skq] = a3;
    *(u16x8*)&Bsm[sr][skq]      = b0;
    *(u16x8*)&Bsm[sr + 32][skq] = b1;
    __syncthreads();

    s16x8 af[4][2], bf[2][2];
    #pragma unroll
    for (int fm = 0; fm < 4; ++fm)
      #pragma unroll
      for (int kk = 0; kk < 2; ++kk)
        af[fm][kk] = *(const s16x8*)&Asm[wm * 64 + fm * 16 + fr][kf + kk * 32];
    #pragma unroll
    for (int fn = 0; fn < 2; ++fn)
      #pragma unroll
      for (int kk = 0; kk < 2; ++kk)
        bf[fn][kk] = *(const s16x8*)&Bsm[wn * 32 + fn * 16 + fr][kf + kk * 32];

    #pragma unroll
    for (int fm = 0; fm < 4; ++fm)
      #pragma unroll
      for (int fn = 0; fn < 2; ++fn) {
        acc[fm][fn] = __builtin_amdgcn_mfma_f32_16x16x32_bf16(af[fm][0], bf[fn][0], acc[fm][fn], 0, 0, 0);
        acc[fm][fn] = __builtin_amdgcn_mfma_f32_16x16x32_bf16(af[fm][1], bf[fn][1], acc[fm][fn], 0, 0, 0);
      }
  }

  const int rg = (lane >> 4) * 4;
  #pragma unroll
  for (int fm = 0; fm < 4; ++fm) {
    #pragma unroll
    for (int fn = 0; fn < 2; ++fn) {
      const int col = bn + wn * 32 + fn * 16 + fr;
      const float bb = bias ? bias[col] : 0.f;
      #pragma unroll
      for (int r = 0; r < 4; ++r) {
        const int row = bm + wm * 64 + fm * 16 + rg + r;
        const float vv = acc[fm][fn][r] + bb;
        if (OUT_BF16) ((unsigned short*)Cout)[(size_t)row * N + col] = f2bf(vv);
        else          ((float*)Cout)[(size_t)row * N + col] = vv;
      }
    }
  }
}

// ---------------------------------------------------------------
// Fused attention. block = (qtile 64, h, b), 256 threads.
// Q,K,VW bf16. LDS 34816B -> 4 blocks/CU.
// USE_PB=1: write per-head P to Pb (attm reduced separately).
// USE_PB=0: atomicAdd attm (fallback if ws too small).
// ---------------------------------------------------------------
template<int USE_PB>
__global__ __launch_bounds__(256) void attn_kernel(
    const unsigned short* __restrict__ Qbf,   // [B*256][1024]
    const unsigned short* __restrict__ KVW,   // [B*256][2048]  (K | VW)
    const int* __restrict__ adj, const float* __restrict__ lab,
    const float* __restrict__ bo,
    float* __restrict__ outp, float* __restrict__ attm,
    unsigned short* __restrict__ Pb)
{
  const int t  = threadIdx.x;
  const int tx = t & 15, ty = t >> 4;
  const int qt = blockIdx.x, h = blockIdx.y, b = blockIdx.z;
  const int q0 = qt * 64;

  __shared__ __align__(16) char smem[34816];
  float (*Qs)[68]          = (float (*)[68])smem;             // [d][q]
  float (*Kc)[68]          = (float (*)[68])(smem + 17408);   // [d][k_local]
  unsigned short (*Ps)[68] = (unsigned short (*)[68])smem;    // [k][q] bf16 (overlays)

  // ---- stage Q^T (bf16 -> f32) ----
  {
    const int qr = t >> 2, d0 = (t & 3) * 16;
    const unsigned short* qrow = Qbf + (size_t)(b * 256 + q0 + qr) * 1024 + h * 64 + d0;
    const u16x8 v0 = *(const u16x8*)qrow;
    const u16x8 v1 = *(const u16x8*)(qrow + 8);
    #pragma unroll
    for (int j = 0; j < 8; ++j) {
      Qs[d0 + j][qr]     = bf2f(v0[j]);
      Qs[d0 + 8 + j][qr] = bf2f(v1[j]);
    }
  }

  // ---- logits over 4 k-chunks ----
  float l[4][16];
  for (int kc = 0; kc < 4; ++kc) {
    __syncthreads();
    {
      const int kl = t >> 2, d0 = (t & 3) * 16;
      const unsigned short* krow = KVW + (size_t)(b * 256 + kc * 64 + kl) * 2048 + h * 64 + d0;
      const u16x8 v0 = *(const u16x8*)krow;
      const u16x8 v1 = *(const u16x8*)(krow + 8);
      #pragma unroll
      for (int j = 0; j < 8; ++j) {
        Kc[d0 + j][kl]     = bf2f(v0[j]);
        Kc[d0 + 8 + j][kl] = bf2f(v1[j]);
      }
    }
    __syncthreads();
    float acc[4][4] = {};
    #pragma unroll 8
    for (int d = 0; d < 64; ++d) {
      const float4 a = *(const float4*)&Qs[d][ty * 4];
      const float4 w = *(const float4*)&Kc[d][tx * 4];
      const float av[4] = {a.x, a.y, a.z, a.w};
      const float wv[4] = {w.x, w.y, w.z, w.w};
      #pragma unroll
      for (int i = 0; i < 4; ++i)
        #pragma unroll
        for (int jj = 0; jj < 4; ++jj)
          acc[i][jj] = fmaf(av[i], wv[jj], acc[i][jj]);
    }
    #pragma unroll
    for (int i = 0; i < 4; ++i)
      #pragma unroll
      for (int jj = 0; jj < 4; ++jj)
        l[i][kc * 4 + jj] = acc[i][jj];
  }

  // ---- mask + bias + softmax ----
  const float scale = 0.125f;
  float inv[4];
  #pragma unroll
  for (int i = 0; i < 4; ++i) {
    const size_t qg = (size_t)b * 256 + q0 + ty * 4 + i;
    const int*   arow = adj + qg * 256;
    const float* brow = lab + qg * 256;
    #pragma unroll
    for (int j4 = 0; j4 < 4; ++j4) {
      const int kb = j4 * 64 + tx * 4;
      const int4   a4 = *(const int4*)(arow + kb);
      const float4 b4 = *(const float4*)(brow + kb);
      float* lp = &l[i][j4 * 4];
      lp[0] = (a4.x > 0 ? lp[0] * scale : NEGF) + b4.x;
      lp[1] = (a4.y > 0 ? lp[1] * scale : NEGF) + b4.y;
      lp[2] = (a4.z > 0 ? lp[2] * scale : NEGF) + b4.z;
      lp[3] = (a4.w > 0 ? lp[3] * scale : NEGF) + b4.w;
    }
    float m = l[i][0];
    #pragma unroll
    for (int n = 1; n < 16; ++n) m = fmaxf(m, l[i][n]);
    #pragma unroll
    for (int off = 1; off < 16; off <<= 1) m = fmaxf(m, __shfl_xor(m, off));
    float s = 0.f;
    #pragma unroll
    for (int n = 0; n < 16; ++n) { l[i][n] = __expf(l[i][n] - m); s += l[i][n]; }
    #pragma unroll
    for (int off = 1; off < 16; off <<= 1) s += __shfl_xor(s, off);
    inv[i] = 1.f / s;
  }

  __syncthreads();  // Qs/Kc dead; Ps overlays

  // ---- P -> LDS bf16 [k][q] ----
  #pragma unroll
  for (int n = 0; n < 16; ++n) {
    const int kg = (n >> 2) * 64 + tx * 4 + (n & 3);
    ushort4 u;
    u.x = f2bf(l[0][n] * inv[0]);
    u.y = f2bf(l[1][n] * inv[1]);
    u.z = f2bf(l[2][n] * inv[2]);
    u.w = f2bf(l[3][n] * inv[3]);
    *(ushort4*)&Ps[kg][ty * 4] = u;
  }

  if (USE_PB) {
    // per-head P rows (coalesced 8B runs); attm reduced in a second kernel
    #pragma unroll
    for (int i = 0; i < 4; ++i) {
      unsigned short* prow = Pb + (((size_t)(b * 16 + h)) * 256 + q0 + ty * 4 + i) * 256;
      const float sc = inv[i];
      #pragma unroll
      for (int j4 = 0; j4 < 4; ++j4) {
        ushort4 u;
        u.x = f2bf(l[i][j4 * 4 + 0] * sc);
        u.y = f2bf(l[i][j4 * 4 + 1] * sc);
        u.z = f2bf(l[i][j4 * 4 + 2] * sc);
        u.w = f2bf(l[i][j4 * 4 + 3] * sc);
        *(ushort4*)(prow + j4 * 64 + tx * 4) = u;
      }
    }
  } else {
    #pragma unroll
    for (int i = 0; i < 4; ++i) {
      const size_t qg = (size_t)b * 256 + q0 + ty * 4 + i;
      float* amrow = attm + qg * 256;
      const float wgt = inv[i] * 0.0625f;
      #pragma unroll
      for (int n = 0; n < 16; ++n) {
        const int kg = (n >> 2) * 64 + tx * 4 + (n & 3);
        atomicAdd(amrow + kg, l[i][n] * wgt);
      }
    }
  }

  __syncthreads();

  // ---- PV: out[q][d] = sum_k P[k][q] * VW[k][d]  (VW from global, L1-resident) ----
  float o[4][4] = {};
  const unsigned short* vwp = KVW + (size_t)(b * 256) * 2048 + 1024 + h * 64 + tx * 4;
  #pragma unroll 4
  for (int k = 0; k < 256; ++k) {
    const ushort4 pu = *(const ushort4*)&Ps[k][ty * 4];
    const ushort4 vv = *(const ushort4*)(vwp + (size_t)k * 2048);
    const float pv[4] = {bf2f(pu.x), bf2f(pu.y), bf2f(pu.z), bf2f(pu.w)};
    const float wv[4] = {bf2f(vv.x), bf2f(vv.y), bf2f(vv.z), bf2f(vv.w)};
    #pragma unroll
    for (int i = 0; i < 4; ++i)
      #pragma unroll
      for (int j = 0; j < 4; ++j)
        o[i][j] = fmaf(pv[i], wv[j], o[i][j]);
  }

  const float4 bo4 = *(const float4*)(bo + h * 64 + tx * 4);
  #pragma unroll
  for (int i = 0; i < 4; ++i) {
    float4 r;
    r.x = o[i][0] + bo4.x; r.y = o[i][1] + bo4.y;
    r.z = o[i][2] + bo4.z; r.w = o[i][3] + bo4.w;
    *(float4*)(outp + (size_t)(b * 256 + q0 + ty * 4 + i) * 1024 + h * 64 + tx * 4) = r;
  }
}

// attm[b][q][k] = (1/16) sum_h Pb[b][h][q][k]
__global__ __launch_bounds__(256) void attm_reduce(
    const unsigned short* __restrict__ Pb, float* __restrict__ attm)
{
  const size_t idx = (size_t)blockIdx.x * 256 + threadIdx.x;  // 131072 total
  const int    k8  = (int)(idx & 31);
  const size_t bq  = idx >> 5;              // b*256+q
  const int    b   = (int)(bq >> 8);
  const int    q   = (int)(bq & 255);
  float s[8] = {};
  const unsigned short* base = Pb + (size_t)b * 1048576 + (size_t)q * 256 + k8 * 8;
  #pragma unroll
  for (int hh = 0; hh < 16; ++hh) {
    const u16x8 p = *(const u16x8*)(base + (size_t)hh * 65536);
    #pragma unroll
    for (int j = 0; j < 8; ++j) s[j] += bf2f(p[j]);
  }
  float* dst = attm + bq * 256 + k8 * 8;
  float4 r0, r1;
  r0.x = s[0] * 0.0625f; r0.y = s[1] * 0.0625f; r0.z = s[2] * 0.0625f; r0.w = s[3] * 0.0625f;
  r1.x = s[4] * 0.0625f; r1.y = s[5] * 0.0625f; r1.z = s[6] * 0.0625f; r1.w = s[7] * 0.0625f;
  *(float4*)dst = r0;
  *(float4*)(dst + 4) = r1;
}

// ---------------------------------------------------------------
extern "C" void kernel_launch(void* const* d_in, const int* in_sizes, int n_in,
                              void* d_out, int out_size, void* d_ws, size_t ws_size,
                              hipStream_t stream)
{
  const float* obj   = (const float*)d_in[0];
  const float* cross = (const float*)d_in[1];
  const int*   adj   = (const int*)d_in[2];
  const float* lab   = (const float*)d_in[3];
  const float* Wq    = (const float*)d_in[4];
  const float* bq    = (const float*)d_in[5];
  const float* Wk    = (const float*)d_in[6];
  const float* bk    = (const float*)d_in[7];
  const float* Wv    = (const float*)d_in[8];
  const float* bv    = (const float*)d_in[9];
  const float* Wo    = (const float*)d_in[10];
  const float* bo    = (const float*)d_in[11];

  float* out  = (float*)d_out;
  float* attm = out + (size_t)16 * 256 * 1024;

  // workspace layout (bytes)
  char* ws = (char*)d_ws;
  unsigned short* obj_bf   = (unsigned short*)(ws + 0);          //  8 MB
  unsigned short* cross_bf = (unsigned short*)(ws + 8388608);    //  8 MB
  unsigned short* Qbf      = (unsigned short*)(ws + 16777216);   //  8 MB
  unsigned short* KVWbf    = (unsigned short*)(ws + 25165824);   // 16 MB [4096][2048]
  unsigned short* Wq_bf    = (unsigned short*)(ws + 41943040);   //  2 MB
  unsigned short* WkWov_bf = (unsigned short*)(ws + 44040192);   //  4 MB [2048][1024]
  unsigned short* Wo_bf    = (unsigned short*)(ws + 48234496);   //  2 MB
  unsigned short* Wvt_bf   = (unsigned short*)(ws + 50331648);   //  2 MB
  float*          biasKV   = (float*)(ws + 52428800);            //  8 KB  (bk | bov)
  unsigned short* Pbuf     = (unsigned short*)(ws + 52436992);   // 32 MB
  const bool usePb = ws_size >= (size_t)85991424;

  // fp32 -> bf16 conversions
  cvt_bf16<<<4096, 256, 0, stream>>>(obj,   obj_bf,   4194304);
  cvt_bf16<<<4096, 256, 0, stream>>>(cross, cross_bf, 4194304);
  cvt_bf16<<<1024, 256, 0, stream>>>(Wq, Wq_bf,    1048576);
  cvt_bf16<<<1024, 256, 0, stream>>>(Wk, WkWov_bf, 1048576);     // rows 0..1023 = Wk
  cvt_bf16<<<1024, 256, 0, stream>>>(Wo, Wo_bf,    1048576);
  tcvt_bf16<<<dim3(32, 32), 256, 0, stream>>>(Wv, Wvt_bf, 1024, 1024);

  // bias for KVW gemm: [bk | bov], bov = Wo @ bv
  hipMemcpyAsync(biasKV, bk, 1024 * sizeof(float), hipMemcpyDeviceToDevice, stream);
  bov_kernel<<<256, 256, 0, stream>>>(Wo, bv, biasKV + 1024);

  // Wov = Wo @ Wv  (bf16 out, into WkWov rows 1024..2047)
  gemm_mfma_bt<1><<<dim3(16, 8), 256, 0, stream>>>(
      Wo_bf, Wvt_bf, nullptr, WkWov_bf + (size_t)1024 * 1024, 1024, 1024, 1024);

  // Q = obj @ Wq^T + bq  (bf16)
  gemm_mfma_bt<1><<<dim3(16, 32), 256, 0, stream>>>(
      obj_bf, Wq_bf, bq, Qbf, 4096, 1024, 1024);

  // [K | VW] = cross @ [Wk | Wov]^T + [bk | bov]  (bf16)
  gemm_mfma_bt<1><<<dim3(32, 32), 256, 0, stream>>>(
      cross_bf, WkWov_bf, biasKV, KVWbf, 4096, 2048, 1024);

  if (usePb) {
    attn_kernel<1><<<dim3(4, 16, 16), 256, 0, stream>>>(
        Qbf, KVWbf, adj, lab, bo, out, attm, Pbuf);
    attm_reduce<<<512, 256, 0, stream>>>(Pbuf, attm);
  } else {
    hipMemsetAsync(attm, 0, (size_t)16 * 256 * 256 * sizeof(float), stream);
    attn_kernel<0><<<dim3(4, 16, 16), 256, 0, stream>>>(
        Qbf, KVWbf, adj, lab, bo, out, attm, Pbuf);
  }
}

// Round 3
// 187.374 us; speedup vs baseline: 3.6467x; 1.0610x over previous
//
#include <hip/hip_runtime.h>

#define NEGF -9e15f

typedef __attribute__((ext_vector_type(8))) unsigned short u16x8;
typedef __attribute__((ext_vector_type(8))) short          s16x8;
typedef __attribute__((ext_vector_type(4))) float          f32x4;

// ---------- bf16 helpers (RTN-even) ----------
__device__ __forceinline__ unsigned short f2bf(float x) {
  union { float f; unsigned int u; } c; c.f = x;
  unsigned int r = c.u + 0x7fffu + ((c.u >> 16) & 1u);
  return (unsigned short)(r >> 16);
}
__device__ __forceinline__ float bf2f(unsigned short v) {
  union { float f; unsigned int u; } c; c.u = ((unsigned int)v) << 16;
  return c.f;
}

// ---------- fp32 -> bf16 elementwise ----------
__global__ __launch_bounds__(256) void cvt_bf16(
    const float* __restrict__ in, unsigned short* __restrict__ out, int n)
{
  const int i = (blockIdx.x * 256 + threadIdx.x) * 4;
  if (i < n) {
    const float4 v = *(const float4*)(in + i);
    ushort4 o; o.x = f2bf(v.x); o.y = f2bf(v.y); o.z = f2bf(v.z); o.w = f2bf(v.w);
    *(ushort4*)(out + i) = o;
  }
}

// ---------- fp32 -> bf16 transposed (out[c][r] = in[r][c]) ----------
__global__ __launch_bounds__(256) void tcvt_bf16(
    const float* __restrict__ in, unsigned short* __restrict__ out, int R, int C)
{
  __shared__ float tile[32][33];
  const int bc = blockIdx.x * 32, br = blockIdx.y * 32;
  const int tx = threadIdx.x & 31, ty8 = threadIdx.x >> 5;
  #pragma unroll
  for (int j = 0; j < 32; j += 8)
    tile[ty8 + j][tx] = in[(size_t)(br + ty8 + j) * C + bc + tx];
  __syncthreads();
  #pragma unroll
  for (int j = 0; j < 32; j += 8)
    out[(size_t)(bc + ty8 + j) * R + br + tx] = f2bf(tile[tx][ty8 + j]);
}

// bov[g] = sum_f Wo[g][f] * bv[f]
__global__ __launch_bounds__(256) void bov_kernel(
    const float* __restrict__ Wo, const float* __restrict__ bv,
    float* __restrict__ bov)
{
  const int g    = blockIdx.x * 4 + (threadIdx.x >> 6);
  const int lane = threadIdx.x & 63;
  float acc = 0.f;
  for (int f = lane; f < 1024; f += 64)
    acc = fmaf(Wo[(size_t)g * 1024 + f], bv[f], acc);
  #pragma unroll
  for (int off = 32; off > 0; off >>= 1) acc += __shfl_down(acc, off);
  if (lane == 0) bov[g] = acc;
}

// ---------------------------------------------------------------
// MFMA GEMM: C = (A[M][K] @ B[N][K]^T + bias) * scale, bf16 out.
// TRANS_STORE=false: C[row][col] row-major [M][N].
// TRANS_STORE=true (requires N==1024): C stored as [b][col][token]
//   with b=row>>8, token=row&255  (i.e. VWt[b*1024+col][256]).
// BM=128 BN=64 BK=64, 256 threads = 4 waves.
// ---------------------------------------------------------------
template<bool TRANS_STORE>
__global__ __launch_bounds__(256) void gemm_mfma_bt(
    const unsigned short* __restrict__ A,
    const unsigned short* __restrict__ Bw,
    const float* __restrict__ bias,
    unsigned short* __restrict__ Cout,
    int M, int N, int K, float scale)
{
  __shared__ unsigned short Asm[128][72];
  __shared__ unsigned short Bsm[64][72];
  const int t = threadIdx.x;
  const int lane = t & 63, w = t >> 6;
  const int wm = w >> 1, wn = w & 1;
  const int bm = blockIdx.y * 128, bn = blockIdx.x * 64;

  f32x4 acc[4][2] = {};

  const int sr  = t >> 3;
  const int skq = (t & 7) * 8;
  const int fr  = lane & 15;
  const int kf  = (lane >> 4) * 8;

  for (int k0 = 0; k0 < K; k0 += 64) {
    const u16x8 a0 = *(const u16x8*)(A  + (size_t)(bm + sr)      * K + k0 + skq);
    const u16x8 a1 = *(const u16x8*)(A  + (size_t)(bm + sr + 32) * K + k0 + skq);
    const u16x8 a2 = *(const u16x8*)(A  + (size_t)(bm + sr + 64) * K + k0 + skq);
    const u16x8 a3 = *(const u16x8*)(A  + (size_t)(bm + sr + 96) * K + k0 + skq);
    const u16x8 b0 = *(const u16x8*)(Bw + (size_t)(bn + sr)      * K + k0 + skq);
    const u16x8 b1 = *(const u16x8*)(Bw + (size_t)(bn + sr + 32) * K + k0 + skq);
    __syncthreads();
    *(u16x8*)&Asm[sr][skq]      = a0;
    *(u16x8*)&Asm[sr + 32][skq] = a1;
    *(u16x8*)&Asm[sr + 64][skq] = a2;
    *(u16x8*)&Asm[sr + 96][skq] = a3;
    *(u16x8*)&Bsm[sr][skq]      = b0;
    *(u16x8*)&Bsm[sr + 32][skq] = b1;
    __syncthreads();

    s16x8 af[4][2], bf[2][2];
    #pragma unroll
    for (int fm = 0; fm < 4; ++fm)
      #pragma unroll
      for (int kk = 0; kk < 2; ++kk)
        af[fm][kk] = *(const s16x8*)&Asm[wm * 64 + fm * 16 + fr][kf + kk * 32];
    #pragma unroll
    for (int fn = 0; fn < 2; ++fn)
      #pragma unroll
      for (int kk = 0; kk < 2; ++kk)
        bf[fn][kk] = *(const s16x8*)&Bsm[wn * 32 + fn * 16 + fr][kf + kk * 32];

    #pragma unroll
    for (int fm = 0; fm < 4; ++fm)
      #pragma unroll
      for (int fn = 0; fn < 2; ++fn) {
        acc[fm][fn] = __builtin_amdgcn_mfma_f32_16x16x32_bf16(af[fm][0], bf[fn][0], acc[fm][fn], 0, 0, 0);
        acc[fm][fn] = __builtin_amdgcn_mfma_f32_16x16x32_bf16(af[fm][1], bf[fn][1], acc[fm][fn], 0, 0, 0);
      }
  }

  const int rg = (lane >> 4) * 4;
  #pragma unroll
  for (int fm = 0; fm < 4; ++fm) {
    #pragma unroll
    for (int fn = 0; fn < 2; ++fn) {
      const int col = bn + wn * 32 + fn * 16 + fr;
      const float bb = bias ? bias[col] : 0.f;
      if (!TRANS_STORE) {
        #pragma unroll
        for (int r = 0; r < 4; ++r) {
          const int row = bm + wm * 64 + fm * 16 + rg + r;
          Cout[(size_t)row * N + col] = f2bf((acc[fm][fn][r] + bb) * scale);
        }
      } else {
        const int row0 = bm + wm * 64 + fm * 16 + rg;
        const int bidx = row0 >> 8, tok = row0 & 255;
        ushort4 u;
        u.x = f2bf((acc[fm][fn][0] + bb) * scale);
        u.y = f2bf((acc[fm][fn][1] + bb) * scale);
        u.z = f2bf((acc[fm][fn][2] + bb) * scale);
        u.w = f2bf((acc[fm][fn][3] + bb) * scale);
        *(ushort4*)(Cout + ((size_t)bidx * 1024 + col) * 256 + tok) = u;
      }
    }
  }
}

// ---------------------------------------------------------------
// MFMA attention. Grid (qt 4, h 16, b 16), 256 threads = 4 waves.
// Wave w owns q rows [qt*64 + w*16, +16), all 256 k, one head.
// Q pre-scaled by 1/8 in its projection GEMM.
// No __syncthreads: each wave uses only its own LDS slab.
// ---------------------------------------------------------------
__global__ __launch_bounds__(256) void attn_mfma(
    const unsigned short* __restrict__ Qg,    // [B*256][1024] bf16, scaled
    const unsigned short* __restrict__ Kg,    // [B*256][1024] bf16
    const unsigned short* __restrict__ VWt,   // [B*1024][256] bf16 ([b][h*64+d][k])
    const int* __restrict__ adj, const float* __restrict__ lab,
    const float* __restrict__ bo,
    float* __restrict__ outp, unsigned short* __restrict__ Pb)
{
  const int t = threadIdx.x;
  const int w = t >> 6, lane = t & 63;
  const int fr = lane & 15, grp = lane >> 4;
  const int qt = blockIdx.x, h = blockIdx.y, b = blockIdx.z;
  const int q0 = qt * 64 + w * 16;

  __shared__ unsigned short Ps[4][16][264];   // per-wave P slab, padded

  // ---- Q A-frags (m = fr, k = grp*8+j | +32) ----
  const unsigned short* qp = Qg + ((size_t)(b * 256 + q0 + fr)) * 1024 + h * 64 + grp * 8;
  const s16x8 qf0 = *(const s16x8*)qp;
  const s16x8 qf1 = *(const s16x8*)(qp + 32);

  // ---- S = Q K^T  (C layout: row q = grp*4+reg, col k = nf*16+fr) ----
  f32x4 s[16];
  #pragma unroll
  for (int nf = 0; nf < 16; ++nf) s[nf] = (f32x4){0.f, 0.f, 0.f, 0.f};
  const unsigned short* kp = Kg + ((size_t)(b * 256 + fr)) * 1024 + h * 64 + grp * 8;
  #pragma unroll
  for (int nf = 0; nf < 16; ++nf) {
    const s16x8 kf0 = *(const s16x8*)(kp + (size_t)nf * 16384);
    const s16x8 kf1 = *(const s16x8*)(kp + (size_t)nf * 16384 + 32);
    s[nf] = __builtin_amdgcn_mfma_f32_16x16x32_bf16(qf0, kf0, s[nf], 0, 0, 0);
    s[nf] = __builtin_amdgcn_mfma_f32_16x16x32_bf16(qf1, kf1, s[nf], 0, 0, 0);
  }

  // ---- mask + label bias, row max (rows live in 16-lane groups) ----
  const size_t qgbase = ((size_t)b * 256 + q0 + grp * 4) * 256 + fr;
  float mx[4] = {-3e38f, -3e38f, -3e38f, -3e38f};
  #pragma unroll
  for (int nf = 0; nf < 16; ++nf)
    #pragma unroll
    for (int r = 0; r < 4; ++r) {
      const size_t off = qgbase + (size_t)r * 256 + nf * 16;
      const float v = (adj[off] > 0 ? s[nf][r] : NEGF) + lab[off];
      s[nf][r] = v;
      mx[r] = fmaxf(mx[r], v);
    }
  #pragma unroll
  for (int r = 0; r < 4; ++r) {
    mx[r] = fmaxf(mx[r], __shfl_xor(mx[r], 1));
    mx[r] = fmaxf(mx[r], __shfl_xor(mx[r], 2));
    mx[r] = fmaxf(mx[r], __shfl_xor(mx[r], 4));
    mx[r] = fmaxf(mx[r], __shfl_xor(mx[r], 8));
  }

  // ---- exp + row sum ----
  float sm[4] = {0.f, 0.f, 0.f, 0.f};
  #pragma unroll
  for (int nf = 0; nf < 16; ++nf)
    #pragma unroll
    for (int r = 0; r < 4; ++r) {
      const float e = __expf(s[nf][r] - mx[r]);
      s[nf][r] = e;
      sm[r] += e;
    }
  #pragma unroll
  for (int r = 0; r < 4; ++r) {
    sm[r] += __shfl_xor(sm[r], 1);
    sm[r] += __shfl_xor(sm[r], 2);
    sm[r] += __shfl_xor(sm[r], 4);
    sm[r] += __shfl_xor(sm[r], 8);
    sm[r] = 1.f / sm[r];
  }

  // ---- P -> LDS (bf16, [q_local][k]) ----
  #pragma unroll
  for (int nf = 0; nf < 16; ++nf)
    #pragma unroll
    for (int r = 0; r < 4; ++r)
      Ps[w][grp * 4 + r][nf * 16 + fr] = f2bf(s[nf][r] * sm[r]);

  // ---- Pb copy (coalesced 16B) for attm reduce ----
  const int half = lane >> 5, c32 = lane & 31;
  #pragma unroll
  for (int it = 0; it < 8; ++it) {
    const int row = it * 2 + half;
    const u16x8 pv = *(const u16x8*)&Ps[w][row][c32 * 8];
    *(u16x8*)(Pb + (((size_t)(b * 16 + h)) * 256 + q0 + row) * 256 + c32 * 8) = pv;
  }

  // ---- O = P @ VW   (A = P from LDS, B = VWt rows, n = d) ----
  f32x4 o[4];
  #pragma unroll
  for (int nf = 0; nf < 4; ++nf) o[nf] = (f32x4){0.f, 0.f, 0.f, 0.f};
  const unsigned short* vp = VWt + ((size_t)(b * 16 + h) * 64 + fr) * 256 + grp * 8;
  #pragma unroll
  for (int ks = 0; ks < 8; ++ks) {
    const s16x8 pf = *(const s16x8*)&Ps[w][fr][ks * 32 + grp * 8];
    #pragma unroll
    for (int nf = 0; nf < 4; ++nf) {
      const s16x8 vf = *(const s16x8*)(vp + (size_t)nf * 4096 + ks * 32);
      o[nf] = __builtin_amdgcn_mfma_f32_16x16x32_bf16(pf, vf, o[nf], 0, 0, 0);
    }
  }

  // ---- epilogue: + bo, store f32 ----
  #pragma unroll
  for (int nf = 0; nf < 4; ++nf) {
    const float bb = bo[h * 64 + nf * 16 + fr];
    #pragma unroll
    for (int r = 0; r < 4; ++r)
      outp[((size_t)b * 256 + q0 + grp * 4 + r) * 1024 + h * 64 + nf * 16 + fr]
          = o[nf][r] + bb;
  }
}

// attm[b][q][k] = (1/16) sum_h Pb[b][h][q][k]
__global__ __launch_bounds__(256) void attm_reduce(
    const unsigned short* __restrict__ Pb, float* __restrict__ attm)
{
  const size_t idx = (size_t)blockIdx.x * 256 + threadIdx.x;
  const int    k8  = (int)(idx & 31);
  const size_t bq  = idx >> 5;
  const int    b   = (int)(bq >> 8);
  const int    q   = (int)(bq & 255);
  float s[8] = {};
  const unsigned short* base = Pb + (size_t)b * 1048576 + (size_t)q * 256 + k8 * 8;
  #pragma unroll
  for (int hh = 0; hh < 16; ++hh) {
    const u16x8 p = *(const u16x8*)(base + (size_t)hh * 65536);
    #pragma unroll
    for (int j = 0; j < 8; ++j) s[j] += bf2f(p[j]);
  }
  float* dst = attm + bq * 256 + k8 * 8;
  float4 r0, r1;
  r0.x = s[0] * 0.0625f; r0.y = s[1] * 0.0625f; r0.z = s[2] * 0.0625f; r0.w = s[3] * 0.0625f;
  r1.x = s[4] * 0.0625f; r1.y = s[5] * 0.0625f; r1.z = s[6] * 0.0625f; r1.w = s[7] * 0.0625f;
  *(float4*)dst = r0;
  *(float4*)(dst + 4) = r1;
}

// ---------------------------------------------------------------
extern "C" void kernel_launch(void* const* d_in, const int* in_sizes, int n_in,
                              void* d_out, int out_size, void* d_ws, size_t ws_size,
                              hipStream_t stream)
{
  const float* obj   = (const float*)d_in[0];
  const float* cross = (const float*)d_in[1];
  const int*   adj   = (const int*)d_in[2];
  const float* lab   = (const float*)d_in[3];
  const float* Wq    = (const float*)d_in[4];
  const float* bq    = (const float*)d_in[5];
  const float* Wk    = (const float*)d_in[6];
  const float* bk    = (const float*)d_in[7];
  const float* Wv    = (const float*)d_in[8];
  const float* bv    = (const float*)d_in[9];
  const float* Wo    = (const float*)d_in[10];
  const float* bo    = (const float*)d_in[11];

  float* out  = (float*)d_out;
  float* attm = out + (size_t)16 * 256 * 1024;

  // workspace layout (bytes) — total 85,987,328 (round-2 verified ws >= 85,991,424)
  char* ws = (char*)d_ws;
  unsigned short* obj_bf   = (unsigned short*)(ws + 0);          //  8 MB
  unsigned short* cross_bf = (unsigned short*)(ws + 8388608);    //  8 MB
  unsigned short* Qbf      = (unsigned short*)(ws + 16777216);   //  8 MB
  unsigned short* Kbf      = (unsigned short*)(ws + 25165824);   //  8 MB
  unsigned short* VWt      = (unsigned short*)(ws + 33554432);   //  8 MB [B*1024][256]
  unsigned short* Wq_bf    = (unsigned short*)(ws + 41943040);   //  2 MB
  unsigned short* Wk_bf    = (unsigned short*)(ws + 44040192);   //  2 MB
  unsigned short* Wo_bf    = (unsigned short*)(ws + 46137344);   //  2 MB
  unsigned short* Wvt_bf   = (unsigned short*)(ws + 48234496);   //  2 MB
  unsigned short* Wov_bf   = (unsigned short*)(ws + 50331648);   //  2 MB
  float*          bov      = (float*)(ws + 52428800);            //  4 KB
  unsigned short* Pbuf     = (unsigned short*)(ws + 52432896);   // 32 MB

  // fp32 -> bf16 conversions
  cvt_bf16<<<4096, 256, 0, stream>>>(obj,   obj_bf,   4194304);
  cvt_bf16<<<4096, 256, 0, stream>>>(cross, cross_bf, 4194304);
  cvt_bf16<<<1024, 256, 0, stream>>>(Wq, Wq_bf, 1048576);
  cvt_bf16<<<1024, 256, 0, stream>>>(Wk, Wk_bf, 1048576);
  cvt_bf16<<<1024, 256, 0, stream>>>(Wo, Wo_bf, 1048576);
  tcvt_bf16<<<dim3(32, 32), 256, 0, stream>>>(Wv, Wvt_bf, 1024, 1024);
  bov_kernel<<<256, 256, 0, stream>>>(Wo, bv, bov);

  // Wov = Wo @ Wv
  gemm_mfma_bt<false><<<dim3(16, 8), 256, 0, stream>>>(
      Wo_bf, Wvt_bf, nullptr, Wov_bf, 1024, 1024, 1024, 1.f);

  // Q = (obj @ Wq^T + bq) * 1/8   (attention scale folded in)
  gemm_mfma_bt<false><<<dim3(16, 32), 256, 0, stream>>>(
      obj_bf, Wq_bf, bq, Qbf, 4096, 1024, 1024, 0.125f);

  // K = cross @ Wk^T + bk
  gemm_mfma_bt<false><<<dim3(16, 32), 256, 0, stream>>>(
      cross_bf, Wk_bf, bk, Kbf, 4096, 1024, 1024, 1.f);

  // VWt = (cross @ Wov^T + bov), stored transposed per batch: [b][col][token]
  gemm_mfma_bt<true><<<dim3(16, 32), 256, 0, stream>>>(
      cross_bf, Wov_bf, bov, VWt, 4096, 1024, 1024, 1.f);

  attn_mfma<<<dim3(4, 16, 16), 256, 0, stream>>>(
      Qbf, Kbf, VWt, adj, lab, bo, out, Pbuf);
  attm_reduce<<<512, 256, 0, stream>>>(Pbuf, attm);
}

// Round 4
// 165.652 us; speedup vs baseline: 4.1249x; 1.1311x over previous
//
#include <hip/hip_runtime.h>

#define NEGF -9e15f

typedef __attribute__((ext_vector_type(8))) unsigned short u16x8;
typedef __attribute__((ext_vector_type(8))) short          s16x8;
typedef __attribute__((ext_vector_type(4))) float          f32x4;

// ---------- bf16 helpers (RTN-even) ----------
__device__ __forceinline__ unsigned short f2bf(float x) {
  union { float f; unsigned int u; } c; c.f = x;
  unsigned int r = c.u + 0x7fffu + ((c.u >> 16) & 1u);
  return (unsigned short)(r >> 16);
}
__device__ __forceinline__ float bf2f(unsigned short v) {
  union { float f; unsigned int u; } c; c.u = ((unsigned int)v) << 16;
  return c.f;
}

// ---------- fp32 -> bf16 elementwise ----------
__global__ __launch_bounds__(256) void cvt_bf16(
    const float* __restrict__ in, unsigned short* __restrict__ out, int n)
{
  const int i = (blockIdx.x * 256 + threadIdx.x) * 4;
  if (i < n) {
    const float4 v = *(const float4*)(in + i);
    ushort4 o; o.x = f2bf(v.x); o.y = f2bf(v.y); o.z = f2bf(v.z); o.w = f2bf(v.w);
    *(ushort4*)(out + i) = o;
  }
}

// ---------- fp32 -> bf16 transposed (out[c][r] = in[r][c]) ----------
__global__ __launch_bounds__(256) void tcvt_bf16(
    const float* __restrict__ in, unsigned short* __restrict__ out, int R, int C)
{
  __shared__ float tile[32][33];
  const int bc = blockIdx.x * 32, br = blockIdx.y * 32;
  const int tx = threadIdx.x & 31, ty8 = threadIdx.x >> 5;
  #pragma unroll
  for (int j = 0; j < 32; j += 8)
    tile[ty8 + j][tx] = in[(size_t)(br + ty8 + j) * C + bc + tx];
  __syncthreads();
  #pragma unroll
  for (int j = 0; j < 32; j += 8)
    out[(size_t)(bc + ty8 + j) * R + br + tx] = f2bf(tile[tx][ty8 + j]);
}

// bov[g] = sum_f Wo[g][f] * bv[f]
__global__ __launch_bounds__(256) void bov_kernel(
    const float* __restrict__ Wo, const float* __restrict__ bv,
    float* __restrict__ bov)
{
  const int g    = blockIdx.x * 4 + (threadIdx.x >> 6);
  const int lane = threadIdx.x & 63;
  float acc = 0.f;
  for (int f = lane; f < 1024; f += 64)
    acc = fmaf(Wo[(size_t)g * 1024 + f], bv[f], acc);
  #pragma unroll
  for (int off = 32; off > 0; off >>= 1) acc += __shfl_down(acc, off);
  if (lane == 0) bov[g] = acc;
}

// mb[i] = adj[i] > 0 ? lab[i] : NEG   (masked logits are exactly NEG in f32)
__global__ __launch_bounds__(256) void mb_prep(
    const int* __restrict__ adj, const float* __restrict__ lab,
    float* __restrict__ mb)
{
  const int i = (blockIdx.x * 256 + threadIdx.x) * 4;
  const int4   a = *(const int4*)(adj + i);
  const float4 l = *(const float4*)(lab + i);
  float4 o;
  o.x = a.x > 0 ? l.x : NEGF;
  o.y = a.y > 0 ? l.y : NEGF;
  o.z = a.z > 0 ? l.z : NEGF;
  o.w = a.w > 0 ? l.w : NEGF;
  *(float4*)(mb + i) = o;
}

// ---------------------------------------------------------------
// MFMA GEMM: C = (A[M][K] @ B[N][K]^T + bias) * scale, bf16 out.
// TRANS_STORE=true (requires N==1024): C stored as [b][col][token].
// BM=128 BN=64 BK=64, 256 threads = 4 waves.
// ---------------------------------------------------------------
template<bool TRANS_STORE>
__global__ __launch_bounds__(256) void gemm_mfma_bt(
    const unsigned short* __restrict__ A,
    const unsigned short* __restrict__ Bw,
    const float* __restrict__ bias,
    unsigned short* __restrict__ Cout,
    int M, int N, int K, float scale)
{
  __shared__ unsigned short Asm[128][72];
  __shared__ unsigned short Bsm[64][72];
  const int t = threadIdx.x;
  const int lane = t & 63, w = t >> 6;
  const int wm = w >> 1, wn = w & 1;
  const int bm = blockIdx.y * 128, bn = blockIdx.x * 64;

  f32x4 acc[4][2] = {};

  const int sr  = t >> 3;
  const int skq = (t & 7) * 8;
  const int fr  = lane & 15;
  const int kf  = (lane >> 4) * 8;

  for (int k0 = 0; k0 < K; k0 += 64) {
    const u16x8 a0 = *(const u16x8*)(A  + (size_t)(bm + sr)      * K + k0 + skq);
    const u16x8 a1 = *(const u16x8*)(A  + (size_t)(bm + sr + 32) * K + k0 + skq);
    const u16x8 a2 = *(const u16x8*)(A  + (size_t)(bm + sr + 64) * K + k0 + skq);
    const u16x8 a3 = *(const u16x8*)(A  + (size_t)(bm + sr + 96) * K + k0 + skq);
    const u16x8 b0 = *(const u16x8*)(Bw + (size_t)(bn + sr)      * K + k0 + skq);
    const u16x8 b1 = *(const u16x8*)(Bw + (size_t)(bn + sr + 32) * K + k0 + skq);
    __syncthreads();
    *(u16x8*)&Asm[sr][skq]      = a0;
    *(u16x8*)&Asm[sr + 32][skq] = a1;
    *(u16x8*)&Asm[sr + 64][skq] = a2;
    *(u16x8*)&Asm[sr + 96][skq] = a3;
    *(u16x8*)&Bsm[sr][skq]      = b0;
    *(u16x8*)&Bsm[sr + 32][skq] = b1;
    __syncthreads();

    s16x8 af[4][2], bf[2][2];
    #pragma unroll
    for (int fm = 0; fm < 4; ++fm)
      #pragma unroll
      for (int kk = 0; kk < 2; ++kk)
        af[fm][kk] = *(const s16x8*)&Asm[wm * 64 + fm * 16 + fr][kf + kk * 32];
    #pragma unroll
    for (int fn = 0; fn < 2; ++fn)
      #pragma unroll
      for (int kk = 0; kk < 2; ++kk)
        bf[fn][kk] = *(const s16x8*)&Bsm[wn * 32 + fn * 16 + fr][kf + kk * 32];

    #pragma unroll
    for (int fm = 0; fm < 4; ++fm)
      #pragma unroll
      for (int fn = 0; fn < 2; ++fn) {
        acc[fm][fn] = __builtin_amdgcn_mfma_f32_16x16x32_bf16(af[fm][0], bf[fn][0], acc[fm][fn], 0, 0, 0);
        acc[fm][fn] = __builtin_amdgcn_mfma_f32_16x16x32_bf16(af[fm][1], bf[fn][1], acc[fm][fn], 0, 0, 0);
      }
  }

  const int rg = (lane >> 4) * 4;
  #pragma unroll
  for (int fm = 0; fm < 4; ++fm) {
    #pragma unroll
    for (int fn = 0; fn < 2; ++fn) {
      const int col = bn + wn * 32 + fn * 16 + fr;
      const float bb = bias ? bias[col] : 0.f;
      if (!TRANS_STORE) {
        #pragma unroll
        for (int r = 0; r < 4; ++r) {
          const int row = bm + wm * 64 + fm * 16 + rg + r;
          Cout[(size_t)row * N + col] = f2bf((acc[fm][fn][r] + bb) * scale);
        }
      } else {
        const int row0 = bm + wm * 64 + fm * 16 + rg;
        const int bidx = row0 >> 8, tok = row0 & 255;
        ushort4 u;
        u.x = f2bf((acc[fm][fn][0] + bb) * scale);
        u.y = f2bf((acc[fm][fn][1] + bb) * scale);
        u.z = f2bf((acc[fm][fn][2] + bb) * scale);
        u.w = f2bf((acc[fm][fn][3] + bb) * scale);
        *(ushort4*)(Cout + ((size_t)bidx * 1024 + col) * 256 + tok) = u;
      }
    }
  }
}

// ---------------------------------------------------------------
// MFMA attention, swapped-QK^T form: S^T = mfma(K, Q).
// Grid: 1024 blocks 1D; decode qt=bid>>8 so the 4 qt-blocks sharing a
// (b,h) K/VW slice land on the same XCD (bid%8 round-robin, 256%8==0).
// 256 threads = 4 waves; wave w owns q rows [qt*64+w*16, +16).
// Lane (fr,grp) after S^T: holds P[q=fr][k=16nf+4grp+r]  (vector-friendly).
// ---------------------------------------------------------------
__global__ __launch_bounds__(256, 3) void attn_mfma(
    const unsigned short* __restrict__ Qg,    // [B*256][1024] bf16, pre-scaled 1/8
    const unsigned short* __restrict__ Kg,    // [B*256][1024] bf16
    const unsigned short* __restrict__ VWt,   // [B*1024][256] bf16 ([b][h*64+d][k])
    const float* __restrict__ mb,             // [B][256][256] masked bias
    const float* __restrict__ bo,
    float* __restrict__ outp, unsigned short* __restrict__ Pb)
{
  const int t = threadIdx.x;
  const int w = t >> 6, lane = t & 63;
  const int fr = lane & 15, grp = lane >> 4;
  const int bid = blockIdx.x;
  const int qt = bid >> 8, hb = bid & 255;
  const int h = hb & 15, b = hb >> 4;
  const int q0 = qt * 64 + w * 16;

  __shared__ unsigned short Ps[4][16][264];   // per-wave P slab [q_local][k]

  // ---- Q B-frags (n = fr = q, k-dim = d = grp*8+j | +32) ----
  const unsigned short* qp = Qg + ((size_t)(b * 256 + q0 + fr)) * 1024 + h * 64 + grp * 8;
  const s16x8 qf0 = *(const s16x8*)qp;
  const s16x8 qf1 = *(const s16x8*)(qp + 32);

  // ---- S^T = K Q^T, interleaved with mb loads ----
  // A-frag: K[k = nf*16 + fr][d = grp*8+j | +32]
  // C-layout: lane (fr,grp) -> S^T[k = nf*16 + grp*4 + r][q = fr]
  f32x4 s[16];
  float4 mb4[16];
  #pragma unroll
  for (int nf = 0; nf < 16; ++nf) s[nf] = (f32x4){0.f, 0.f, 0.f, 0.f};
  const unsigned short* kp = Kg + ((size_t)(b * 256 + fr)) * 1024 + h * 64 + grp * 8;
  const float* mbp = mb + ((size_t)(b * 256 + q0 + fr)) * 256 + grp * 4;
  #pragma unroll
  for (int nf = 0; nf < 16; ++nf) {
    const s16x8 kf0 = *(const s16x8*)(kp + (size_t)nf * 16384);
    const s16x8 kf1 = *(const s16x8*)(kp + (size_t)nf * 16384 + 32);
    mb4[nf] = *(const float4*)(mbp + nf * 16);
    s[nf] = __builtin_amdgcn_mfma_f32_16x16x32_bf16(kf0, qf0, s[nf], 0, 0, 0);
    s[nf] = __builtin_amdgcn_mfma_f32_16x16x32_bf16(kf1, qf1, s[nf], 0, 0, 0);
  }

  // ---- mask + bias + row max (row q = fr, spread over 4 grp lanes) ----
  float mx = -3e38f;
  #pragma unroll
  for (int nf = 0; nf < 16; ++nf) {
    #pragma unroll
    for (int r = 0; r < 4; ++r) {
      const float m = ((const float*)&mb4[nf])[r];
      const float v = (m > -1e14f) ? s[nf][r] + m : m;
      s[nf][r] = v;
      mx = fmaxf(mx, v);
    }
  }
  mx = fmaxf(mx, __shfl_xor(mx, 16));
  mx = fmaxf(mx, __shfl_xor(mx, 32));

  // ---- exp + row sum ----
  float sm = 0.f;
  #pragma unroll
  for (int nf = 0; nf < 16; ++nf) {
    #pragma unroll
    for (int r = 0; r < 4; ++r) {
      const float e = __expf(s[nf][r] - mx);
      s[nf][r] = e;
      sm += e;
    }
  }
  sm += __shfl_xor(sm, 16);
  sm += __shfl_xor(sm, 32);
  const float inv = 1.f / sm;

  // ---- P -> LDS [q][k] (ushort4) + Pb direct from regs ----
  unsigned short* prow = Pb + (((size_t)(b * 16 + h)) * 256 + q0 + fr) * 256 + grp * 4;
  #pragma unroll
  for (int nf = 0; nf < 16; ++nf) {
    ushort4 u;
    u.x = f2bf(s[nf][0] * inv);
    u.y = f2bf(s[nf][1] * inv);
    u.z = f2bf(s[nf][2] * inv);
    u.w = f2bf(s[nf][3] * inv);
    *(ushort4*)&Ps[w][fr][nf * 16 + grp * 4] = u;
    *(ushort4*)(prow + nf * 16) = u;
  }

  // ---- O = P @ VW  (A = P from LDS, B-frag: VWt[d = nf*16 + fr][k]) ----
  f32x4 o[4];
  #pragma unroll
  for (int nf = 0; nf < 4; ++nf) o[nf] = (f32x4){0.f, 0.f, 0.f, 0.f};
  const unsigned short* vp = VWt + ((size_t)(b * 16 + h) * 64 + fr) * 256 + grp * 8;
  #pragma unroll
  for (int ks = 0; ks < 8; ++ks) {
    const s16x8 pf = *(const s16x8*)&Ps[w][fr][ks * 32 + grp * 8];
    #pragma unroll
    for (int nf = 0; nf < 4; ++nf) {
      const s16x8 vf = *(const s16x8*)(vp + (size_t)nf * 4096 + ks * 32);
      o[nf] = __builtin_amdgcn_mfma_f32_16x16x32_bf16(pf, vf, o[nf], 0, 0, 0);
    }
  }

  // ---- epilogue: + bo, store f32 (lane holds O[q=grp*4+r][d=nf*16+fr]) ----
  #pragma unroll
  for (int nf = 0; nf < 4; ++nf) {
    const float bb = bo[h * 64 + nf * 16 + fr];
    #pragma unroll
    for (int r = 0; r < 4; ++r)
      outp[((size_t)b * 256 + q0 + grp * 4 + r) * 1024 + h * 64 + nf * 16 + fr]
          = o[nf][r] + bb;
  }
}

// attm[b][q][k] = (1/16) sum_h Pb[b][h][q][k]
__global__ __launch_bounds__(256) void attm_reduce(
    const unsigned short* __restrict__ Pb, float* __restrict__ attm)
{
  const size_t idx = (size_t)blockIdx.x * 256 + threadIdx.x;
  const int    k8  = (int)(idx & 31);
  const size_t bq  = idx >> 5;
  const int    b   = (int)(bq >> 8);
  const int    q   = (int)(bq & 255);
  float s[8] = {};
  const unsigned short* base = Pb + (size_t)b * 1048576 + (size_t)q * 256 + k8 * 8;
  #pragma unroll
  for (int hh = 0; hh < 16; ++hh) {
    const u16x8 p = *(const u16x8*)(base + (size_t)hh * 65536);
    #pragma unroll
    for (int j = 0; j < 8; ++j) s[j] += bf2f(p[j]);
  }
  float* dst = attm + bq * 256 + k8 * 8;
  float4 r0, r1;
  r0.x = s[0] * 0.0625f; r0.y = s[1] * 0.0625f; r0.z = s[2] * 0.0625f; r0.w = s[3] * 0.0625f;
  r1.x = s[4] * 0.0625f; r1.y = s[5] * 0.0625f; r1.z = s[6] * 0.0625f; r1.w = s[7] * 0.0625f;
  *(float4*)dst = r0;
  *(float4*)(dst + 4) = r1;
}

// ---------------------------------------------------------------
extern "C" void kernel_launch(void* const* d_in, const int* in_sizes, int n_in,
                              void* d_out, int out_size, void* d_ws, size_t ws_size,
                              hipStream_t stream)
{
  const float* obj   = (const float*)d_in[0];
  const float* cross = (const float*)d_in[1];
  const int*   adj   = (const int*)d_in[2];
  const float* lab   = (const float*)d_in[3];
  const float* Wq    = (const float*)d_in[4];
  const float* bq    = (const float*)d_in[5];
  const float* Wk    = (const float*)d_in[6];
  const float* bk    = (const float*)d_in[7];
  const float* Wv    = (const float*)d_in[8];
  const float* bv    = (const float*)d_in[9];
  const float* Wo    = (const float*)d_in[10];
  const float* bo    = (const float*)d_in[11];

  float* out  = (float*)d_out;
  float* attm = out + (size_t)16 * 256 * 1024;

  // workspace layout (bytes) — total 85,987,328 (verified ws >= 85,991,424)
  char* ws = (char*)d_ws;
  unsigned short* obj_bf   = (unsigned short*)(ws + 0);          //  8 MB (reused as mb after Q gemm)
  unsigned short* cross_bf = (unsigned short*)(ws + 8388608);    //  8 MB
  unsigned short* Qbf      = (unsigned short*)(ws + 16777216);   //  8 MB
  unsigned short* Kbf      = (unsigned short*)(ws + 25165824);   //  8 MB
  unsigned short* VWt      = (unsigned short*)(ws + 33554432);   //  8 MB [B*1024][256]
  unsigned short* Wq_bf    = (unsigned short*)(ws + 41943040);   //  2 MB
  unsigned short* Wk_bf    = (unsigned short*)(ws + 44040192);   //  2 MB
  unsigned short* Wo_bf    = (unsigned short*)(ws + 46137344);   //  2 MB
  unsigned short* Wvt_bf   = (unsigned short*)(ws + 48234496);   //  2 MB
  unsigned short* Wov_bf   = (unsigned short*)(ws + 50331648);   //  2 MB
  float*          bov      = (float*)(ws + 52428800);            //  4 KB
  unsigned short* Pbuf     = (unsigned short*)(ws + 52432896);   // 32 MB
  float*          mbuf     = (float*)obj_bf;                     //  4 MB (aliases obj_bf)

  // fp32 -> bf16 conversions
  cvt_bf16<<<4096, 256, 0, stream>>>(obj,   obj_bf,   4194304);
  cvt_bf16<<<4096, 256, 0, stream>>>(cross, cross_bf, 4194304);
  cvt_bf16<<<1024, 256, 0, stream>>>(Wq, Wq_bf, 1048576);
  cvt_bf16<<<1024, 256, 0, stream>>>(Wk, Wk_bf, 1048576);
  cvt_bf16<<<1024, 256, 0, stream>>>(Wo, Wo_bf, 1048576);
  tcvt_bf16<<<dim3(32, 32), 256, 0, stream>>>(Wv, Wvt_bf, 1024, 1024);
  bov_kernel<<<256, 256, 0, stream>>>(Wo, bv, bov);

  // Wov = Wo @ Wv
  gemm_mfma_bt<false><<<dim3(16, 8), 256, 0, stream>>>(
      Wo_bf, Wvt_bf, nullptr, Wov_bf, 1024, 1024, 1024, 1.f);

  // Q = (obj @ Wq^T + bq) * 1/8   (attention scale folded in)
  gemm_mfma_bt<false><<<dim3(16, 32), 256, 0, stream>>>(
      obj_bf, Wq_bf, bq, Qbf, 4096, 1024, 1024, 0.125f);

  // obj_bf is dead now -> build masked-bias table in its place
  mb_prep<<<1024, 256, 0, stream>>>(adj, lab, mbuf);

  // K = cross @ Wk^T + bk
  gemm_mfma_bt<false><<<dim3(16, 32), 256, 0, stream>>>(
      cross_bf, Wk_bf, bk, Kbf, 4096, 1024, 1024, 1.f);

  // VWt = (cross @ Wov^T + bov), stored transposed per batch: [b][col][token]
  gemm_mfma_bt<true><<<dim3(16, 32), 256, 0, stream>>>(
      cross_bf, Wov_bf, bov, VWt, 4096, 1024, 1024, 1.f);

  attn_mfma<<<1024, 256, 0, stream>>>(
      Qbf, Kbf, VWt, mbuf, bo, out, Pbuf);
  attm_reduce<<<512, 256, 0, stream>>>(Pbuf, attm);
}

// Round 5
// 143.583 us; speedup vs baseline: 4.7589x; 1.1537x over previous
//
#include <hip/hip_runtime.h>

#define NEGF -9e15f

typedef __attribute__((ext_vector_type(8))) unsigned short u16x8;
typedef __attribute__((ext_vector_type(8))) short          s16x8;
typedef __attribute__((ext_vector_type(4))) float          f32x4;

// ---------- bf16 helpers (RTN-even) ----------
__device__ __forceinline__ unsigned short f2bf(float x) {
  union { float f; unsigned int u; } c; c.f = x;
  unsigned int r = c.u + 0x7fffu + ((c.u >> 16) & 1u);
  return (unsigned short)(r >> 16);
}
__device__ __forceinline__ float bf2f(unsigned short v) {
  union { float f; unsigned int u; } c; c.u = ((unsigned int)v) << 16;
  return c.f;
}

// ---------- async global->LDS, 16B per lane (wave-uniform LDS base) ----------
__device__ __forceinline__ void gload16(const void* g, void* l) {
  __builtin_amdgcn_global_load_lds(
      (const __attribute__((address_space(1))) unsigned int*)g,
      (__attribute__((address_space(3))) unsigned int*)l, 16, 0, 0);
}

// ---------- fp32 -> bf16 elementwise (optional scale) ----------
__global__ __launch_bounds__(256) void cvt_bf16(
    const float* __restrict__ in, unsigned short* __restrict__ out, int n, float scale)
{
  const int i = (blockIdx.x * 256 + threadIdx.x) * 4;
  if (i < n) {
    const float4 v = *(const float4*)(in + i);
    ushort4 o;
    o.x = f2bf(v.x * scale); o.y = f2bf(v.y * scale);
    o.z = f2bf(v.z * scale); o.w = f2bf(v.w * scale);
    *(ushort4*)(out + i) = o;
  }
}

// ---------- fp32 -> bf16 transposed (out[c][r] = in[r][c]) ----------
__global__ __launch_bounds__(256) void tcvt_bf16(
    const float* __restrict__ in, unsigned short* __restrict__ out, int R, int C)
{
  __shared__ float tile[32][33];
  const int bc = blockIdx.x * 32, br = blockIdx.y * 32;
  const int tx = threadIdx.x & 31, ty8 = threadIdx.x >> 5;
  #pragma unroll
  for (int j = 0; j < 32; j += 8)
    tile[ty8 + j][tx] = in[(size_t)(br + ty8 + j) * C + bc + tx];
  __syncthreads();
  #pragma unroll
  for (int j = 0; j < 32; j += 8)
    out[(size_t)(bc + ty8 + j) * R + br + tx] = f2bf(tile[tx][ty8 + j]);
}

// bov[g] = sum_f Wo[g][f] * bv[f]
__global__ __launch_bounds__(256) void bov_kernel(
    const float* __restrict__ Wo, const float* __restrict__ bv,
    float* __restrict__ bov)
{
  const int g    = blockIdx.x * 4 + (threadIdx.x >> 6);
  const int lane = threadIdx.x & 63;
  float acc = 0.f;
  for (int f = lane; f < 1024; f += 64)
    acc = fmaf(Wo[(size_t)g * 1024 + f], bv[f], acc);
  #pragma unroll
  for (int off = 32; off > 0; off >>= 1) acc += __shfl_down(acc, off);
  if (lane == 0) bov[g] = acc;
}

// ball[0:1024) = 0.125*bq ; ball[1024:2048) = bk   (bov fills [2048:3072))
__global__ __launch_bounds__(256) void bias_prep(
    const float* __restrict__ bq, const float* __restrict__ bk,
    float* __restrict__ ball)
{
  const int i = blockIdx.x * 256 + threadIdx.x;
  ball[i]        = 0.125f * bq[i];
  ball[1024 + i] = bk[i];
}

// mb[i] = adj[i] > 0 ? lab[i] : NEG
__global__ __launch_bounds__(256) void mb_prep(
    const int* __restrict__ adj, const float* __restrict__ lab,
    float* __restrict__ mb)
{
  const int i = (blockIdx.x * 256 + threadIdx.x) * 4;
  const int4   a = *(const int4*)(adj + i);
  const float4 l = *(const float4*)(lab + i);
  float4 o;
  o.x = a.x > 0 ? l.x : NEGF;
  o.y = a.y > 0 ? l.y : NEGF;
  o.z = a.z > 0 ? l.z : NEGF;
  o.w = a.w > 0 ? l.w : NEGF;
  *(float4*)(mb + i) = o;
}

// ---------------------------------------------------------------
// Small reg-staged MFMA GEMM (used only for Wov = Wo @ Wv, 1024^3).
// C = A[M][K] @ B[N][K]^T, bf16 out. BM=128 BN=64 BK=64.
// ---------------------------------------------------------------
__global__ __launch_bounds__(256) void gemm_wov(
    const unsigned short* __restrict__ A,
    const unsigned short* __restrict__ Bw,
    unsigned short* __restrict__ Cout,
    int M, int N, int K)
{
  __shared__ unsigned short Asm[128][72];
  __shared__ unsigned short Bsm[64][72];
  const int t = threadIdx.x;
  const int lane = t & 63, w = t >> 6;
  const int wm = w >> 1, wn = w & 1;
  const int bm = blockIdx.y * 128, bn = blockIdx.x * 64;

  f32x4 acc[4][2] = {};

  const int sr  = t >> 3;
  const int skq = (t & 7) * 8;
  const int fr  = lane & 15;
  const int kf  = (lane >> 4) * 8;

  for (int k0 = 0; k0 < K; k0 += 64) {
    const u16x8 a0 = *(const u16x8*)(A  + (size_t)(bm + sr)      * K + k0 + skq);
    const u16x8 a1 = *(const u16x8*)(A  + (size_t)(bm + sr + 32) * K + k0 + skq);
    const u16x8 a2 = *(const u16x8*)(A  + (size_t)(bm + sr + 64) * K + k0 + skq);
    const u16x8 a3 = *(const u16x8*)(A  + (size_t)(bm + sr + 96) * K + k0 + skq);
    const u16x8 b0 = *(const u16x8*)(Bw + (size_t)(bn + sr)      * K + k0 + skq);
    const u16x8 b1 = *(const u16x8*)(Bw + (size_t)(bn + sr + 32) * K + k0 + skq);
    __syncthreads();
    *(u16x8*)&Asm[sr][skq]      = a0;
    *(u16x8*)&Asm[sr + 32][skq] = a1;
    *(u16x8*)&Asm[sr + 64][skq] = a2;
    *(u16x8*)&Asm[sr + 96][skq] = a3;
    *(u16x8*)&Bsm[sr][skq]      = b0;
    *(u16x8*)&Bsm[sr + 32][skq] = b1;
    __syncthreads();

    s16x8 af[4][2], bf[2][2];
    #pragma unroll
    for (int fm = 0; fm < 4; ++fm)
      #pragma unroll
      for (int kk = 0; kk < 2; ++kk)
        af[fm][kk] = *(const s16x8*)&Asm[wm * 64 + fm * 16 + fr][kf + kk * 32];
    #pragma unroll
    for (int fn = 0; fn < 2; ++fn)
      #pragma unroll
      for (int kk = 0; kk < 2; ++kk)
        bf[fn][kk] = *(const s16x8*)&Bsm[wn * 32 + fn * 16 + fr][kf + kk * 32];

    #pragma unroll
    for (int fm = 0; fm < 4; ++fm)
      #pragma unroll
      for (int fn = 0; fn < 2; ++fn) {
        acc[fm][fn] = __builtin_amdgcn_mfma_f32_16x16x32_bf16(af[fm][0], bf[fn][0], acc[fm][fn], 0, 0, 0);
        acc[fm][fn] = __builtin_amdgcn_mfma_f32_16x16x32_bf16(af[fm][1], bf[fn][1], acc[fm][fn], 0, 0, 0);
      }
  }

  const int rg = (lane >> 4) * 4;
  #pragma unroll
  for (int fm = 0; fm < 4; ++fm)
    #pragma unroll
    for (int fn = 0; fn < 2; ++fn) {
      const int col = bn + wn * 32 + fn * 16 + fr;
      #pragma unroll
      for (int r = 0; r < 4; ++r) {
        const int row = bm + wm * 64 + fm * 16 + rg + r;
        Cout[(size_t)row * N + col] = f2bf(acc[fm][fn][r]);
      }
    }
}

// ---------------------------------------------------------------
// Fused projection GEMM (m97 structure): C = A @ Wall^T + ball.
// N = 3072 merged: cols [0,1024)=Q (A=obj, W pre-scaled 1/8),
// [1024,2048)=K (A=cross), [2048,3072)=VW (A=cross, trans-store).
// BM=BN=128, BK=64, 256 threads = 4 waves (2x2), 64x64 per wave.
// Staging via global_load_lds dwordx4, linear LDS, 2 barriers/K-step.
// ---------------------------------------------------------------
__global__ __launch_bounds__(256, 3) void gemm_big(
    const unsigned short* __restrict__ objA,
    const unsigned short* __restrict__ crossA,
    const unsigned short* __restrict__ Wall,   // [3072][1024]
    const float* __restrict__ ball,            // [3072]
    unsigned short* __restrict__ Qo,           // [4096][1024]
    unsigned short* __restrict__ Ko,           // [4096][1024]
    unsigned short* __restrict__ VWt)          // [B*1024][256]
{
  __shared__ unsigned short Asm[128 * 64];
  __shared__ unsigned short Bsm[128 * 64];
  const int t = threadIdx.x;
  const int w = t >> 6, lane = t & 63;
  const int wm = w >> 1, wn = w & 1;
  const int bn = blockIdx.x * 128;
  const int bm = blockIdx.y * 128;
  const unsigned short* Ag = (bn < 1024) ? objA : crossA;

  const int srow = lane >> 3;          // 0..7
  const int skel = (lane & 7) * 8;     // 0..56 (elts)
  const int fr = lane & 15, kf = (lane >> 4) * 8;

  f32x4 acc[4][4] = {};

  for (int k0 = 0; k0 < 1024; k0 += 64) {
    if (k0) __syncthreads();           // all waves done reading previous tile
    #pragma unroll
    for (int i = 0; i < 4; ++i) {
      const int c = i * 4 + w;         // chunk 0..15, 8 rows each
      const int r = c * 8 + srow;
      gload16(Ag   + (size_t)(bm + r) * 1024 + k0 + skel, &Asm[c * 512]);
      gload16(Wall + (size_t)(bn + r) * 1024 + k0 + skel, &Bsm[c * 512]);
    }
    __syncthreads();                   // drains vmcnt -> LDS tile ready
    #pragma unroll
    for (int kk = 0; kk < 2; ++kk) {
      s16x8 af[4], bf[4];
      #pragma unroll
      for (int fm = 0; fm < 4; ++fm)
        af[fm] = *(const s16x8*)&Asm[(wm * 64 + fm * 16 + fr) * 64 + kk * 32 + kf];
      #pragma unroll
      for (int fn = 0; fn < 4; ++fn)
        bf[fn] = *(const s16x8*)&Bsm[(wn * 64 + fn * 16 + fr) * 64 + kk * 32 + kf];
      #pragma unroll
      for (int fm = 0; fm < 4; ++fm)
        #pragma unroll
        for (int fn = 0; fn < 4; ++fn)
          acc[fm][fn] = __builtin_amdgcn_mfma_f32_16x16x32_bf16(af[fm], bf[fn], acc[fm][fn], 0, 0, 0);
    }
  }

  const int rg = (lane >> 4) * 4;
  const int mode = bn >> 10;           // 0=Q 1=K 2=VW (128-tile never straddles)
  #pragma unroll
  for (int fm = 0; fm < 4; ++fm) {
    #pragma unroll
    for (int fn = 0; fn < 4; ++fn) {
      const int col  = bn + wn * 64 + fn * 16 + fr;
      const int cl   = col & 1023;
      const float bb = ball[col];
      const int row0 = bm + wm * 64 + fm * 16 + rg;
      if (mode == 0) {
        #pragma unroll
        for (int r = 0; r < 4; ++r)
          Qo[(size_t)(row0 + r) * 1024 + cl] = f2bf(acc[fm][fn][r] + bb);
      } else if (mode == 1) {
        #pragma unroll
        for (int r = 0; r < 4; ++r)
          Ko[(size_t)(row0 + r) * 1024 + cl] = f2bf(acc[fm][fn][r] + bb);
      } else {
        const int bidx = row0 >> 8, tok = row0 & 255;
        ushort4 u;
        u.x = f2bf(acc[fm][fn][0] + bb);
        u.y = f2bf(acc[fm][fn][1] + bb);
        u.z = f2bf(acc[fm][fn][2] + bb);
        u.w = f2bf(acc[fm][fn][3] + bb);
        *(ushort4*)(VWt + ((size_t)bidx * 1024 + cl) * 256 + tok) = u;
      }
    }
  }
}

// ---------------------------------------------------------------
// MFMA attention, swapped-QK^T form: S^T = mfma(K, Q).  (unchanged r4)
// ---------------------------------------------------------------
__global__ __launch_bounds__(256, 3) void attn_mfma(
    const unsigned short* __restrict__ Qg,    // [B*256][1024] bf16, pre-scaled 1/8
    const unsigned short* __restrict__ Kg,    // [B*256][1024] bf16
    const unsigned short* __restrict__ VWt,   // [B*1024][256] bf16 ([b][h*64+d][k])
    const float* __restrict__ mb,             // [B][256][256] masked bias
    const float* __restrict__ bo,
    float* __restrict__ outp, unsigned short* __restrict__ Pb)
{
  const int t = threadIdx.x;
  const int w = t >> 6, lane = t & 63;
  const int fr = lane & 15, grp = lane >> 4;
  const int bid = blockIdx.x;
  const int qt = bid >> 8, hb = bid & 255;
  const int h = hb & 15, b = hb >> 4;
  const int q0 = qt * 64 + w * 16;

  __shared__ unsigned short Ps[4][16][264];   // per-wave P slab [q_local][k]

  const unsigned short* qp = Qg + ((size_t)(b * 256 + q0 + fr)) * 1024 + h * 64 + grp * 8;
  const s16x8 qf0 = *(const s16x8*)qp;
  const s16x8 qf1 = *(const s16x8*)(qp + 32);

  f32x4 s[16];
  float4 mb4[16];
  #pragma unroll
  for (int nf = 0; nf < 16; ++nf) s[nf] = (f32x4){0.f, 0.f, 0.f, 0.f};
  const unsigned short* kp = Kg + ((size_t)(b * 256 + fr)) * 1024 + h * 64 + grp * 8;
  const float* mbp = mb + ((size_t)(b * 256 + q0 + fr)) * 256 + grp * 4;
  #pragma unroll
  for (int nf = 0; nf < 16; ++nf) {
    const s16x8 kf0 = *(const s16x8*)(kp + (size_t)nf * 16384);
    const s16x8 kf1 = *(const s16x8*)(kp + (size_t)nf * 16384 + 32);
    mb4[nf] = *(const float4*)(mbp + nf * 16);
    s[nf] = __builtin_amdgcn_mfma_f32_16x16x32_bf16(kf0, qf0, s[nf], 0, 0, 0);
    s[nf] = __builtin_amdgcn_mfma_f32_16x16x32_bf16(kf1, qf1, s[nf], 0, 0, 0);
  }

  float mx = -3e38f;
  #pragma unroll
  for (int nf = 0; nf < 16; ++nf) {
    #pragma unroll
    for (int r = 0; r < 4; ++r) {
      const float m = ((const float*)&mb4[nf])[r];
      const float v = (m > -1e14f) ? s[nf][r] + m : m;
      s[nf][r] = v;
      mx = fmaxf(mx, v);
    }
  }
  mx = fmaxf(mx, __shfl_xor(mx, 16));
  mx = fmaxf(mx, __shfl_xor(mx, 32));

  float sm = 0.f;
  #pragma unroll
  for (int nf = 0; nf < 16; ++nf) {
    #pragma unroll
    for (int r = 0; r < 4; ++r) {
      const float e = __expf(s[nf][r] - mx);
      s[nf][r] = e;
      sm += e;
    }
  }
  sm += __shfl_xor(sm, 16);
  sm += __shfl_xor(sm, 32);
  const float inv = 1.f / sm;

  unsigned short* prow = Pb + (((size_t)(b * 16 + h)) * 256 + q0 + fr) * 256 + grp * 4;
  #pragma unroll
  for (int nf = 0; nf < 16; ++nf) {
    ushort4 u;
    u.x = f2bf(s[nf][0] * inv);
    u.y = f2bf(s[nf][1] * inv);
    u.z = f2bf(s[nf][2] * inv);
    u.w = f2bf(s[nf][3] * inv);
    *(ushort4*)&Ps[w][fr][nf * 16 + grp * 4] = u;
    *(ushort4*)(prow + nf * 16) = u;
  }

  f32x4 o[4];
  #pragma unroll
  for (int nf = 0; nf < 4; ++nf) o[nf] = (f32x4){0.f, 0.f, 0.f, 0.f};
  const unsigned short* vp = VWt + ((size_t)(b * 16 + h) * 64 + fr) * 256 + grp * 8;
  #pragma unroll
  for (int ks = 0; ks < 8; ++ks) {
    const s16x8 pf = *(const s16x8*)&Ps[w][fr][ks * 32 + grp * 8];
    #pragma unroll
    for (int nf = 0; nf < 4; ++nf) {
      const s16x8 vf = *(const s16x8*)(vp + (size_t)nf * 4096 + ks * 32);
      o[nf] = __builtin_amdgcn_mfma_f32_16x16x32_bf16(pf, vf, o[nf], 0, 0, 0);
    }
  }

  #pragma unroll
  for (int nf = 0; nf < 4; ++nf) {
    const float bb = bo[h * 64 + nf * 16 + fr];
    #pragma unroll
    for (int r = 0; r < 4; ++r)
      outp[((size_t)b * 256 + q0 + grp * 4 + r) * 1024 + h * 64 + nf * 16 + fr]
          = o[nf][r] + bb;
  }
}

// attm[b][q][k] = (1/16) sum_h Pb[b][h][q][k]
__global__ __launch_bounds__(256) void attm_reduce(
    const unsigned short* __restrict__ Pb, float* __restrict__ attm)
{
  const size_t idx = (size_t)blockIdx.x * 256 + threadIdx.x;
  const int    k8  = (int)(idx & 31);
  const size_t bq  = idx >> 5;
  const int    b   = (int)(bq >> 8);
  const int    q   = (int)(bq & 255);
  float s[8] = {};
  const unsigned short* base = Pb + (size_t)b * 1048576 + (size_t)q * 256 + k8 * 8;
  #pragma unroll
  for (int hh = 0; hh < 16; ++hh) {
    const u16x8 p = *(const u16x8*)(base + (size_t)hh * 65536);
    #pragma unroll
    for (int j = 0; j < 8; ++j) s[j] += bf2f(p[j]);
  }
  float* dst = attm + bq * 256 + k8 * 8;
  float4 r0, r1;
  r0.x = s[0] * 0.0625f; r0.y = s[1] * 0.0625f; r0.z = s[2] * 0.0625f; r0.w = s[3] * 0.0625f;
  r1.x = s[4] * 0.0625f; r1.y = s[5] * 0.0625f; r1.z = s[6] * 0.0625f; r1.w = s[7] * 0.0625f;
  *(float4*)dst = r0;
  *(float4*)(dst + 4) = r1;
}

// ---------------------------------------------------------------
extern "C" void kernel_launch(void* const* d_in, const int* in_sizes, int n_in,
                              void* d_out, int out_size, void* d_ws, size_t ws_size,
                              hipStream_t stream)
{
  const float* obj   = (const float*)d_in[0];
  const float* cross = (const float*)d_in[1];
  const int*   adj   = (const int*)d_in[2];
  const float* lab   = (const float*)d_in[3];
  const float* Wq    = (const float*)d_in[4];
  const float* bq    = (const float*)d_in[5];
  const float* Wk    = (const float*)d_in[6];
  const float* bk    = (const float*)d_in[7];
  const float* Wv    = (const float*)d_in[8];
  const float* bv    = (const float*)d_in[9];
  const float* Wo    = (const float*)d_in[10];
  const float* bo    = (const float*)d_in[11];

  float* out  = (float*)d_out;
  float* attm = out + (size_t)16 * 256 * 1024;

  // workspace layout (bytes) — total 85,987,328 (proven ws fits in r3/r4)
  char* ws = (char*)d_ws;
  unsigned short* obj_bf   = (unsigned short*)(ws + 0);          // 8 MB (mbuf aliases later)
  unsigned short* cross_bf = (unsigned short*)(ws + 8388608);    // 8 MB
  unsigned short* Qbf      = (unsigned short*)(ws + 16777216);   // 8 MB
  unsigned short* Kbf      = (unsigned short*)(ws + 25165824);   // 8 MB
  unsigned short* VWt      = (unsigned short*)(ws + 33554432);   // 8 MB [B*1024][256]
  unsigned short* Wall     = (unsigned short*)(ws + 41943040);   // 6 MB [3072][1024]
  unsigned short* Wo_bf    = (unsigned short*)(ws + 48234496);   // 2 MB
  unsigned short* Wvt_bf   = (unsigned short*)(ws + 50331648);   // 2 MB (ball aliases after Wov gemm)
  float*          ball     = (float*)(ws + 50331648);            // 12 KB
  unsigned short* Pbuf     = (unsigned short*)(ws + 52432896);   // 32 MB
  float*          mbuf     = (float*)obj_bf;                     // 4 MB (after gemm_big)

  // fp32 -> bf16 conversions (Wq pre-scaled by 1/8 — exact in bf16)
  cvt_bf16<<<4096, 256, 0, stream>>>(obj,   obj_bf,   4194304, 1.f);
  cvt_bf16<<<4096, 256, 0, stream>>>(cross, cross_bf, 4194304, 1.f);
  cvt_bf16<<<1024, 256, 0, stream>>>(Wq, Wall,           1048576, 0.125f);
  cvt_bf16<<<1024, 256, 0, stream>>>(Wk, Wall + 1048576, 1048576, 1.f);
  cvt_bf16<<<1024, 256, 0, stream>>>(Wo, Wo_bf,          1048576, 1.f);
  tcvt_bf16<<<dim3(32, 32), 256, 0, stream>>>(Wv, Wvt_bf, 1024, 1024);

  // Wov = Wo @ Wv  -> Wall rows [2048, 3072)
  gemm_wov<<<dim3(16, 8), 256, 0, stream>>>(
      Wo_bf, Wvt_bf, Wall + 2097152, 1024, 1024, 1024);

  // bias vector [0.125*bq | bk | bov]  (aliases Wvt_bf — Wov gemm is done)
  bias_prep<<<4, 256, 0, stream>>>(bq, bk, ball);
  bov_kernel<<<256, 256, 0, stream>>>(Wo, bv, ball + 2048);

  // fused [Q | K | VW] projection, m97-style global_load_lds GEMM
  gemm_big<<<dim3(24, 32), 256, 0, stream>>>(
      obj_bf, cross_bf, Wall, ball, Qbf, Kbf, VWt);

  // obj_bf dead -> masked-bias table
  mb_prep<<<1024, 256, 0, stream>>>(adj, lab, mbuf);

  attn_mfma<<<1024, 256, 0, stream>>>(
      Qbf, Kbf, VWt, mbuf, bo, out, Pbuf);
  attm_reduce<<<512, 256, 0, stream>>>(Pbuf, attm);
}

// Round 6
// 139.301 us; speedup vs baseline: 4.9052x; 1.0307x over previous
//
#include <hip/hip_runtime.h>

#define NEGF -9e15f

typedef __attribute__((ext_vector_type(8))) unsigned short u16x8;
typedef __attribute__((ext_vector_type(8))) short          s16x8;
typedef __attribute__((ext_vector_type(4))) float          f32x4;

// ---------- bf16 helpers (RTN-even) ----------
__device__ __forceinline__ unsigned short f2bf(float x) {
  union { float f; unsigned int u; } c; c.f = x;
  unsigned int r = c.u + 0x7fffu + ((c.u >> 16) & 1u);
  return (unsigned short)(r >> 16);
}
__device__ __forceinline__ float bf2f(unsigned short v) {
  union { float f; unsigned int u; } c; c.u = ((unsigned int)v) << 16;
  return c.f;
}

// ---------- async global->LDS, 16B per lane (wave-uniform LDS base) ----------
__device__ __forceinline__ void gload16(const void* g, void* l) {
  __builtin_amdgcn_global_load_lds(
      (const __attribute__((address_space(1))) unsigned int*)g,
      (__attribute__((address_space(3))) unsigned int*)l, 16, 0, 0);
}

// ---------- fp32 -> bf16 elementwise (optional scale) ----------
__global__ __launch_bounds__(256) void cvt_bf16(
    const float* __restrict__ in, unsigned short* __restrict__ out, int n, float scale)
{
  const int i = (blockIdx.x * 256 + threadIdx.x) * 4;
  if (i < n) {
    const float4 v = *(const float4*)(in + i);
    ushort4 o;
    o.x = f2bf(v.x * scale); o.y = f2bf(v.y * scale);
    o.z = f2bf(v.z * scale); o.w = f2bf(v.w * scale);
    *(ushort4*)(out + i) = o;
  }
}

// ---------- fp32 -> bf16 transposed (out[c][r] = in[r][c]) ----------
__global__ __launch_bounds__(256) void tcvt_bf16(
    const float* __restrict__ in, unsigned short* __restrict__ out, int R, int C)
{
  __shared__ float tile[32][33];
  const int bc = blockIdx.x * 32, br = blockIdx.y * 32;
  const int tx = threadIdx.x & 31, ty8 = threadIdx.x >> 5;
  #pragma unroll
  for (int j = 0; j < 32; j += 8)
    tile[ty8 + j][tx] = in[(size_t)(br + ty8 + j) * C + bc + tx];
  __syncthreads();
  #pragma unroll
  for (int j = 0; j < 32; j += 8)
    out[(size_t)(bc + ty8 + j) * R + br + tx] = f2bf(tile[tx][ty8 + j]);
}

// bov[g] = sum_f Wo[g][f] * bv[f]
__global__ __launch_bounds__(256) void bov_kernel(
    const float* __restrict__ Wo, const float* __restrict__ bv,
    float* __restrict__ bov)
{
  const int g    = blockIdx.x * 4 + (threadIdx.x >> 6);
  const int lane = threadIdx.x & 63;
  float acc = 0.f;
  for (int f = lane; f < 1024; f += 64)
    acc = fmaf(Wo[(size_t)g * 1024 + f], bv[f], acc);
  #pragma unroll
  for (int off = 32; off > 0; off >>= 1) acc += __shfl_down(acc, off);
  if (lane == 0) bov[g] = acc;
}

// ball[0:1024) = 0.125*bq ; ball[1024:2048) = bk
__global__ __launch_bounds__(256) void bias_prep(
    const float* __restrict__ bq, const float* __restrict__ bk,
    float* __restrict__ ball)
{
  const int i = blockIdx.x * 256 + threadIdx.x;
  ball[i]        = 0.125f * bq[i];
  ball[1024 + i] = bk[i];
}

// mb[i] = adj[i] > 0 ? lab[i] : NEG
__global__ __launch_bounds__(256) void mb_prep(
    const int* __restrict__ adj, const float* __restrict__ lab,
    float* __restrict__ mb)
{
  const int i = (blockIdx.x * 256 + threadIdx.x) * 4;
  const int4   a = *(const int4*)(adj + i);
  const float4 l = *(const float4*)(lab + i);
  float4 o;
  o.x = a.x > 0 ? l.x : NEGF;
  o.y = a.y > 0 ? l.y : NEGF;
  o.z = a.z > 0 ? l.z : NEGF;
  o.w = a.w > 0 ? l.w : NEGF;
  *(float4*)(mb + i) = o;
}

// ---------------------------------------------------------------
// Small reg-staged MFMA GEMM (Wov = Wo @ Wv, 1024^3).
// ---------------------------------------------------------------
__global__ __launch_bounds__(256) void gemm_wov(
    const unsigned short* __restrict__ A,
    const unsigned short* __restrict__ Bw,
    unsigned short* __restrict__ Cout,
    int M, int N, int K)
{
  __shared__ unsigned short Asm[128][72];
  __shared__ unsigned short Bsm[64][72];
  const int t = threadIdx.x;
  const int lane = t & 63, w = t >> 6;
  const int wm = w >> 1, wn = w & 1;
  const int bm = blockIdx.y * 128, bn = blockIdx.x * 64;

  f32x4 acc[4][2] = {};

  const int sr  = t >> 3;
  const int skq = (t & 7) * 8;
  const int fr  = lane & 15;
  const int kf  = (lane >> 4) * 8;

  for (int k0 = 0; k0 < K; k0 += 64) {
    const u16x8 a0 = *(const u16x8*)(A  + (size_t)(bm + sr)      * K + k0 + skq);
    const u16x8 a1 = *(const u16x8*)(A  + (size_t)(bm + sr + 32) * K + k0 + skq);
    const u16x8 a2 = *(const u16x8*)(A  + (size_t)(bm + sr + 64) * K + k0 + skq);
    const u16x8 a3 = *(const u16x8*)(A  + (size_t)(bm + sr + 96) * K + k0 + skq);
    const u16x8 b0 = *(const u16x8*)(Bw + (size_t)(bn + sr)      * K + k0 + skq);
    const u16x8 b1 = *(const u16x8*)(Bw + (size_t)(bn + sr + 32) * K + k0 + skq);
    __syncthreads();
    *(u16x8*)&Asm[sr][skq]      = a0;
    *(u16x8*)&Asm[sr + 32][skq] = a1;
    *(u16x8*)&Asm[sr + 64][skq] = a2;
    *(u16x8*)&Asm[sr + 96][skq] = a3;
    *(u16x8*)&Bsm[sr][skq]      = b0;
    *(u16x8*)&Bsm[sr + 32][skq] = b1;
    __syncthreads();

    s16x8 af[4][2], bf[2][2];
    #pragma unroll
    for (int fm = 0; fm < 4; ++fm)
      #pragma unroll
      for (int kk = 0; kk < 2; ++kk)
        af[fm][kk] = *(const s16x8*)&Asm[wm * 64 + fm * 16 + fr][kf + kk * 32];
    #pragma unroll
    for (int fn = 0; fn < 2; ++fn)
      #pragma unroll
      for (int kk = 0; kk < 2; ++kk)
        bf[fn][kk] = *(const s16x8*)&Bsm[wn * 32 + fn * 16 + fr][kf + kk * 32];

    #pragma unroll
    for (int fm = 0; fm < 4; ++fm)
      #pragma unroll
      for (int fn = 0; fn < 2; ++fn) {
        acc[fm][fn] = __builtin_amdgcn_mfma_f32_16x16x32_bf16(af[fm][0], bf[fn][0], acc[fm][fn], 0, 0, 0);
        acc[fm][fn] = __builtin_amdgcn_mfma_f32_16x16x32_bf16(af[fm][1], bf[fn][1], acc[fm][fn], 0, 0, 0);
      }
  }

  const int rg = (lane >> 4) * 4;
  #pragma unroll
  for (int fm = 0; fm < 4; ++fm)
    #pragma unroll
    for (int fn = 0; fn < 2; ++fn) {
      const int col = bn + wn * 32 + fn * 16 + fr;
      #pragma unroll
      for (int r = 0; r < 4; ++r) {
        const int row = bm + wm * 64 + fm * 16 + rg + r;
        Cout[(size_t)row * N + col] = f2bf(acc[fm][fn][r]);
      }
    }
}

// ---------------------------------------------------------------
// Fused projection GEMM (m97 structure, unchanged from r5).
// ---------------------------------------------------------------
__global__ __launch_bounds__(256, 3) void gemm_big(
    const unsigned short* __restrict__ objA,
    const unsigned short* __restrict__ crossA,
    const unsigned short* __restrict__ Wall,   // [3072][1024]
    const float* __restrict__ ball,            // [3072]
    unsigned short* __restrict__ Qo,           // [4096][1024]
    unsigned short* __restrict__ Ko,           // [4096][1024]
    unsigned short* __restrict__ VWt)          // [B*1024][256]
{
  __shared__ unsigned short Asm[128 * 64];
  __shared__ unsigned short Bsm[128 * 64];
  const int t = threadIdx.x;
  const int w = t >> 6, lane = t & 63;
  const int wm = w >> 1, wn = w & 1;
  const int bn = blockIdx.x * 128;
  const int bm = blockIdx.y * 128;
  const unsigned short* Ag = (bn < 1024) ? objA : crossA;

  const int srow = lane >> 3;
  const int skel = (lane & 7) * 8;
  const int fr = lane & 15, kf = (lane >> 4) * 8;

  f32x4 acc[4][4] = {};

  for (int k0 = 0; k0 < 1024; k0 += 64) {
    if (k0) __syncthreads();
    #pragma unroll
    for (int i = 0; i < 4; ++i) {
      const int c = i * 4 + w;
      const int r = c * 8 + srow;
      gload16(Ag   + (size_t)(bm + r) * 1024 + k0 + skel, &Asm[c * 512]);
      gload16(Wall + (size_t)(bn + r) * 1024 + k0 + skel, &Bsm[c * 512]);
    }
    __syncthreads();
    #pragma unroll
    for (int kk = 0; kk < 2; ++kk) {
      s16x8 af[4], bf[4];
      #pragma unroll
      for (int fm = 0; fm < 4; ++fm)
        af[fm] = *(const s16x8*)&Asm[(wm * 64 + fm * 16 + fr) * 64 + kk * 32 + kf];
      #pragma unroll
      for (int fn = 0; fn < 4; ++fn)
        bf[fn] = *(const s16x8*)&Bsm[(wn * 64 + fn * 16 + fr) * 64 + kk * 32 + kf];
      #pragma unroll
      for (int fm = 0; fm < 4; ++fm)
        #pragma unroll
        for (int fn = 0; fn < 4; ++fn)
          acc[fm][fn] = __builtin_amdgcn_mfma_f32_16x16x32_bf16(af[fm], bf[fn], acc[fm][fn], 0, 0, 0);
    }
  }

  const int rg = (lane >> 4) * 4;
  const int mode = bn >> 10;
  #pragma unroll
  for (int fm = 0; fm < 4; ++fm) {
    #pragma unroll
    for (int fn = 0; fn < 4; ++fn) {
      const int col  = bn + wn * 64 + fn * 16 + fr;
      const int cl   = col & 1023;
      const float bb = ball[col];
      const int row0 = bm + wm * 64 + fm * 16 + rg;
      if (mode == 0) {
        #pragma unroll
        for (int r = 0; r < 4; ++r)
          Qo[(size_t)(row0 + r) * 1024 + cl] = f2bf(acc[fm][fn][r] + bb);
      } else if (mode == 1) {
        #pragma unroll
        for (int r = 0; r < 4; ++r)
          Ko[(size_t)(row0 + r) * 1024 + cl] = f2bf(acc[fm][fn][r] + bb);
      } else {
        const int bidx = row0 >> 8, tok = row0 & 255;
        ushort4 u;
        u.x = f2bf(acc[fm][fn][0] + bb);
        u.y = f2bf(acc[fm][fn][1] + bb);
        u.z = f2bf(acc[fm][fn][2] + bb);
        u.w = f2bf(acc[fm][fn][3] + bb);
        *(ushort4*)(VWt + ((size_t)bidx * 1024 + cl) * 256 + tok) = u;
      }
    }
  }
}

// ---------------------------------------------------------------
// MFMA attention v2. S^T = mfma(K, Q); hand-pipelined K loads;
// VW staged LDS via async DMA (source-swizzled); P via shuffles.
// Grid 1024 blocks (qt=bid>>8), 256 threads = 4 waves.
// ---------------------------------------------------------------
__global__ __launch_bounds__(256, 3) void attn_mfma(
    const unsigned short* __restrict__ Qg,    // [B*256][1024] bf16, pre-scaled 1/8
    const unsigned short* __restrict__ Kg,    // [B*256][1024] bf16
    const unsigned short* __restrict__ VWt,   // [B*1024][256] bf16 ([b][h*64+d][k])
    const float* __restrict__ mb,             // [B][256][256] masked bias
    const float* __restrict__ bo,
    float* __restrict__ outp, unsigned short* __restrict__ Pb)
{
  const int t = threadIdx.x;
  const int w = t >> 6, lane = t & 63;
  const int fr = lane & 15, grp = lane >> 4;
  const int bid = blockIdx.x;
  const int qt = bid >> 8, hb = bid & 255;
  const int h = hb & 15, b = hb >> 4;
  const int q0 = qt * 64 + w * 16;

  __shared__ __align__(16) unsigned short VWs[64 * 256];   // 32 KB, XOR-swizzled

  // ---- async DMA: VW slice (b,h) -> LDS. LDS linear; source pre-swizzled
  //      so LDS[row][x] = VW[row][x ^ ((row&7)<<4)]  (byte-level XOR). ----
  {
    const unsigned short* vwb = VWt + (size_t)(b * 16 + h) * 16384;
    const int xb = (lane & 31) * 16;
    #pragma unroll
    for (int c = 0; c < 8; ++c) {
      const int row = c * 8 + w * 2 + (lane >> 5);
      const int sb  = xb ^ ((row & 7) << 4);
      gload16(vwb + row * 256 + (sb >> 1), (char*)VWs + c * 4096 + w * 1024);
    }
  }

  // ---- Q B-frags ----
  const unsigned short* qp = Qg + ((size_t)(b * 256 + q0 + fr)) * 1024 + h * 64 + grp * 8;
  const s16x8 qf0 = *(const s16x8*)qp;
  const s16x8 qf1 = *(const s16x8*)(qp + 32);

  // ---- S^T = K Q^T: 4-nf batches, 2-deep ping-pong, mask folded in ----
  const unsigned short* kp = Kg + ((size_t)(b * 256 + fr)) * 1024 + h * 64 + grp * 8;
  const float* mbp = mb + ((size_t)(b * 256 + q0 + fr)) * 256 + grp * 4;

  f32x4 s[16];
  #pragma unroll
  for (int nf = 0; nf < 16; ++nf) s[nf] = (f32x4){0.f, 0.f, 0.f, 0.f};

  s16x8 kA[8], kB[8];
  float4 mA[4], mB[4];
  float mx = -3e38f;

#define LOADB(KF, MF, nb)                                                    \
  { _Pragma("unroll") for (int i = 0; i < 4; ++i) {                          \
      KF[2*i]   = *(const s16x8*)(kp + (size_t)((nb)*4 + i) * 16384);        \
      KF[2*i+1] = *(const s16x8*)(kp + (size_t)((nb)*4 + i) * 16384 + 32);   \
      MF[i]     = *(const float4*)(mbp + ((nb)*4 + i) * 16); } }
#define MFMAB(KF, nb)                                                        \
  { _Pragma("unroll") for (int i = 0; i < 4; ++i) {                          \
      s[(nb)*4+i] = __builtin_amdgcn_mfma_f32_16x16x32_bf16(KF[2*i],   qf0, s[(nb)*4+i], 0, 0, 0); \
      s[(nb)*4+i] = __builtin_amdgcn_mfma_f32_16x16x32_bf16(KF[2*i+1], qf1, s[(nb)*4+i], 0, 0, 0); } }
#define MASKB(MF, nb)                                                        \
  { _Pragma("unroll") for (int i = 0; i < 4; ++i) {                          \
      _Pragma("unroll") for (int r = 0; r < 4; ++r) {                        \
        const float m = ((const float*)&MF[i])[r];                           \
        const float v = (m > -1e14f) ? s[(nb)*4+i][r] + m : m;               \
        s[(nb)*4+i][r] = v; mx = fmaxf(mx, v); } } }

  LOADB(kA, mA, 0); LOADB(kB, mB, 1); MFMAB(kA, 0);
  MASKB(mA, 0);     LOADB(kA, mA, 2); MFMAB(kB, 1);
  MASKB(mB, 1);     LOADB(kB, mB, 3); MFMAB(kA, 2);
  MASKB(mA, 2);     LOADB(kA, mA, 4); MFMAB(kB, 3);
  MASKB(mB, 3);     LOADB(kB, mB, 5); MFMAB(kA, 4);
  MASKB(mA, 4);     LOADB(kA, mA, 6); MFMAB(kB, 5);
  MASKB(mB, 5);     LOADB(kB, mB, 7); MFMAB(kA, 6);
  MASKB(mA, 6);     MFMAB(kB, 7);     MASKB(mB, 7);
#undef LOADB
#undef MFMAB
#undef MASKB

  // ---- softmax (row q = fr, spread over grp lanes) ----
  mx = fmaxf(mx, __shfl_xor(mx, 16));
  mx = fmaxf(mx, __shfl_xor(mx, 32));
  float sm = 0.f;
  #pragma unroll
  for (int nf = 0; nf < 16; ++nf)
    #pragma unroll
    for (int r = 0; r < 4; ++r) {
      const float e = __expf(s[nf][r] - mx);
      s[nf][r] = e;
      sm += e;
    }
  sm += __shfl_xor(sm, 16);
  sm += __shfl_xor(sm, 32);
  const float inv = 1.f / sm;

  // ---- pack P -> bf16 pairs in registers ----
  uint2 u2[16];
  #pragma unroll
  for (int nf = 0; nf < 16; ++nf) {
    const unsigned lo = (unsigned)f2bf(s[nf][0] * inv) | ((unsigned)f2bf(s[nf][1] * inv) << 16);
    const unsigned hi = (unsigned)f2bf(s[nf][2] * inv) | ((unsigned)f2bf(s[nf][3] * inv) << 16);
    u2[nf] = make_uint2(lo, hi);
  }

  __syncthreads();   // drains VW DMA (vmcnt 0) + all waves' staging done

  // ---- Pb store (from regs; k = 16nf + 4grp + 0..3 for row q0+fr) ----
  unsigned short* prow = Pb + (((size_t)(b * 16 + h)) * 256 + q0 + fr) * 256 + grp * 4;
  #pragma unroll
  for (int nf = 0; nf < 16; ++nf)
    *(uint2*)(prow + nf * 16) = u2[nf];

  // ---- PV: pf via shuffles, vf via swizzled LDS reads ----
  f32x4 o[4];
  #pragma unroll
  for (int nf = 0; nf < 4; ++nf) o[nf] = (f32x4){0.f, 0.f, 0.f, 0.f};
  const int srcA = fr + ((grp & 1) << 5);
  const int srcB = srcA + 16;
  const int swz  = (fr & 7) << 4;
  const bool hiSel = (grp & 2);
  #pragma unroll
  for (int ks = 0; ks < 8; ++ks) {
    const int aLx = __shfl((int)u2[2 * ks].x,     srcA, 64);
    const int aLy = __shfl((int)u2[2 * ks].y,     srcA, 64);
    const int bLx = __shfl((int)u2[2 * ks].x,     srcB, 64);
    const int bLy = __shfl((int)u2[2 * ks].y,     srcB, 64);
    const int aHx = __shfl((int)u2[2 * ks + 1].x, srcA, 64);
    const int aHy = __shfl((int)u2[2 * ks + 1].y, srcA, 64);
    const int bHx = __shfl((int)u2[2 * ks + 1].x, srcB, 64);
    const int bHy = __shfl((int)u2[2 * ks + 1].y, srcB, 64);
    union { int4 i; s16x8 v; } pf;
    pf.i = hiSel ? make_int4(aHx, aHy, bHx, bHy) : make_int4(aLx, aLy, bLx, bLy);
    const int cb = (ks * 64 + grp * 16) ^ swz;
    #pragma unroll
    for (int nf = 0; nf < 4; ++nf) {
      const s16x8 vf = *(const s16x8*)((const char*)VWs + (nf * 16 + fr) * 512 + cb);
      o[nf] = __builtin_amdgcn_mfma_f32_16x16x32_bf16(pf.v, vf, o[nf], 0, 0, 0);
    }
  }

  // ---- epilogue: + bo, store f32 (lane holds O[q=grp*4+r][d=nf*16+fr]) ----
  #pragma unroll
  for (int nf = 0; nf < 4; ++nf) {
    const float bb = bo[h * 64 + nf * 16 + fr];
    #pragma unroll
    for (int r = 0; r < 4; ++r)
      outp[((size_t)b * 256 + q0 + grp * 4 + r) * 1024 + h * 64 + nf * 16 + fr]
          = o[nf][r] + bb;
  }
}

// attm[b][q][k] = (1/16) sum_h Pb[b][h][q][k]
__global__ __launch_bounds__(256) void attm_reduce(
    const unsigned short* __restrict__ Pb, float* __restrict__ attm)
{
  const size_t idx = (size_t)blockIdx.x * 256 + threadIdx.x;
  const int    k8  = (int)(idx & 31);
  const size_t bq  = idx >> 5;
  const int    b   = (int)(bq >> 8);
  const int    q   = (int)(bq & 255);
  float s[8] = {};
  const unsigned short* base = Pb + (size_t)b * 1048576 + (size_t)q * 256 + k8 * 8;
  #pragma unroll
  for (int hh = 0; hh < 16; ++hh) {
    const u16x8 p = *(const u16x8*)(base + (size_t)hh * 65536);
    #pragma unroll
    for (int j = 0; j < 8; ++j) s[j] += bf2f(p[j]);
  }
  float* dst = attm + bq * 256 + k8 * 8;
  float4 r0, r1;
  r0.x = s[0] * 0.0625f; r0.y = s[1] * 0.0625f; r0.z = s[2] * 0.0625f; r0.w = s[3] * 0.0625f;
  r1.x = s[4] * 0.0625f; r1.y = s[5] * 0.0625f; r1.z = s[6] * 0.0625f; r1.w = s[7] * 0.0625f;
  *(float4*)dst = r0;
  *(float4*)(dst + 4) = r1;
}

// ---------------------------------------------------------------
extern "C" void kernel_launch(void* const* d_in, const int* in_sizes, int n_in,
                              void* d_out, int out_size, void* d_ws, size_t ws_size,
                              hipStream_t stream)
{
  const float* obj   = (const float*)d_in[0];
  const float* cross = (const float*)d_in[1];
  const int*   adj   = (const int*)d_in[2];
  const float* lab   = (const float*)d_in[3];
  const float* Wq    = (const float*)d_in[4];
  const float* bq    = (const float*)d_in[5];
  const float* Wk    = (const float*)d_in[6];
  const float* bk    = (const float*)d_in[7];
  const float* Wv    = (const float*)d_in[8];
  const float* bv    = (const float*)d_in[9];
  const float* Wo    = (const float*)d_in[10];
  const float* bo    = (const float*)d_in[11];

  float* out  = (float*)d_out;
  float* attm = out + (size_t)16 * 256 * 1024;

  // workspace layout (bytes)
  char* ws = (char*)d_ws;
  unsigned short* obj_bf   = (unsigned short*)(ws + 0);          // 8 MB (mbuf aliases later)
  unsigned short* cross_bf = (unsigned short*)(ws + 8388608);    // 8 MB
  unsigned short* Qbf      = (unsigned short*)(ws + 16777216);   // 8 MB
  unsigned short* Kbf      = (unsigned short*)(ws + 25165824);   // 8 MB
  unsigned short* VWt      = (unsigned short*)(ws + 33554432);   // 8 MB [B*1024][256]
  unsigned short* Wall     = (unsigned short*)(ws + 41943040);   // 6 MB [3072][1024]
  unsigned short* Wo_bf    = (unsigned short*)(ws + 48234496);   // 2 MB
  unsigned short* Wvt_bf   = (unsigned short*)(ws + 50331648);   // 2 MB (ball aliases after Wov gemm)
  float*          ball     = (float*)(ws + 50331648);            // 12 KB
  unsigned short* Pbuf     = (unsigned short*)(ws + 52432896);   // 32 MB
  float*          mbuf     = (float*)obj_bf;                     // 4 MB (after gemm_big)

  // fp32 -> bf16 conversions (Wq pre-scaled by 1/8 — exact in bf16)
  cvt_bf16<<<4096, 256, 0, stream>>>(obj,   obj_bf,   4194304, 1.f);
  cvt_bf16<<<4096, 256, 0, stream>>>(cross, cross_bf, 4194304, 1.f);
  cvt_bf16<<<1024, 256, 0, stream>>>(Wq, Wall,           1048576, 0.125f);
  cvt_bf16<<<1024, 256, 0, stream>>>(Wk, Wall + 1048576, 1048576, 1.f);
  cvt_bf16<<<1024, 256, 0, stream>>>(Wo, Wo_bf,          1048576, 1.f);
  tcvt_bf16<<<dim3(32, 32), 256, 0, stream>>>(Wv, Wvt_bf, 1024, 1024);

  // Wov = Wo @ Wv  -> Wall rows [2048, 3072)
  gemm_wov<<<dim3(16, 8), 256, 0, stream>>>(
      Wo_bf, Wvt_bf, Wall + 2097152, 1024, 1024, 1024);

  // bias vector [0.125*bq | bk | bov]
  bias_prep<<<4, 256, 0, stream>>>(bq, bk, ball);
  bov_kernel<<<256, 256, 0, stream>>>(Wo, bv, ball + 2048);

  // fused [Q | K | VW] projection
  gemm_big<<<dim3(24, 32), 256, 0, stream>>>(
      obj_bf, cross_bf, Wall, ball, Qbf, Kbf, VWt);

  // obj_bf dead -> masked-bias table
  mb_prep<<<1024, 256, 0, stream>>>(adj, lab, mbuf);

  attn_mfma<<<1024, 256, 0, stream>>>(
      Qbf, Kbf, VWt, mbuf, bo, out, Pbuf);
  attm_reduce<<<512, 256, 0, stream>>>(Pbuf, attm);
}